// Round 4
// baseline (588.315 us; speedup 1.0000x reference)
//
#include <hip/hip_runtime.h>
#include <cstdint>
#include <cstddef>

constexpr int N_NODES = 100000;
constexpr int N_EDGES = 1600000;
constexpr int F_IN   = 128;
constexpr int F_HID  = 128;
constexpr int F_OUT  = 40;
constexpr float BN_EPS = 1e-5f;

constexpr int NBUCK  = 196;      // ceil(100000 / 512), bucket = dst >> 9
constexpr int ECHUNK = 4096;     // edges per partition block
constexpr int NCHUNK = (N_EDGES + ECHUNK - 1) / ECHUNK;   // 391

typedef unsigned int uint;
typedef unsigned short ushort;

// ---------------- helpers ----------------
__device__ inline uint bf16_rne(float f) {
    uint u = __float_as_uint(f);
    return (u + 0x7fffu + ((u >> 16) & 1u)) >> 16;
}
__device__ inline float bf_lo(uint u) { return __uint_as_float(u << 16); }
__device__ inline float bf_hi(uint u) { return __uint_as_float(u & 0xffff0000u); }

// ---------------- CSR build: bucketed two-level ----------------
// Pass A: histogram of dst buckets.
__global__ __launch_bounds__(256) void k_hist(const int* __restrict__ dst,
                                              int* __restrict__ gcnt) {
    __shared__ int hist[NBUCK];
    for (int i = threadIdx.x; i < NBUCK; i += 256) hist[i] = 0;
    __syncthreads();
    int base = blockIdx.x * ECHUNK;
    int n = min(ECHUNK, N_EDGES - base);
    for (int i = threadIdx.x; i < n; i += 256)
        atomicAdd(&hist[dst[base + i] >> 9], 1);
    __syncthreads();
    for (int i = threadIdx.x; i < NBUCK; i += 256)
        if (hist[i]) atomicAdd(&gcnt[i], hist[i]);
}

// Scan bucket counts -> bucket offsets (boff) and fill cursors (gfill).
__global__ void k_bscan(const int* __restrict__ gcnt, int* __restrict__ boff,
                        int* __restrict__ gfill, int* __restrict__ rowptr) {
    __shared__ int s[256];
    int t = threadIdx.x;
    int c = (t < NBUCK) ? gcnt[t] : 0;
    s[t] = c;
    __syncthreads();
    #pragma unroll
    for (int o = 1; o < 256; o <<= 1) {
        int v = (t >= o) ? s[t - o] : 0;
        __syncthreads();
        s[t] += v;
        __syncthreads();
    }
    if (t < NBUCK) { int e = s[t] - c; boff[t] = e; gfill[t] = e; }
    if (t == 0) { boff[NBUCK] = N_EDGES; rowptr[N_NODES] = N_EDGES; }
}

// Pass B: LDS multi-split partition of edges into bucket-ordered ebuf.
__global__ __launch_bounds__(256) void k_part(const int* __restrict__ src,
                                              const int* __restrict__ dst,
                                              int* __restrict__ gfill,
                                              uint2* __restrict__ ebuf) {
    __shared__ uint2 pairs[ECHUNK];          // 32 KB
    __shared__ uint  gd[ECHUNK];             // 16 KB
    __shared__ int hist[NBUCK], loff[NBUCK], gpos[NBUCK], lfill[NBUCK];
    __shared__ int sc[256];
    int t = threadIdx.x;
    for (int i = t; i < NBUCK; i += 256) { hist[i] = 0; lfill[i] = 0; }
    __syncthreads();
    int base = blockIdx.x * ECHUNK;
    int n = min(ECHUNK, N_EDGES - base);
    for (int i = t; i < n; i += 256)
        atomicAdd(&hist[dst[base + i] >> 9], 1);
    __syncthreads();
    int c = (t < NBUCK) ? hist[t] : 0;
    sc[t] = c;
    __syncthreads();
    #pragma unroll
    for (int o = 1; o < 256; o <<= 1) {
        int v = (t >= o) ? sc[t - o] : 0;
        __syncthreads();
        sc[t] += v;
        __syncthreads();
    }
    if (t < NBUCK) {
        loff[t] = sc[t] - c;
        gpos[t] = c ? atomicAdd(&gfill[t], c) : 0;
    }
    __syncthreads();
    for (int i = t; i < n; i += 256) {
        int d = dst[base + i];
        int s2 = src[base + i];
        int b = d >> 9;
        int lp = atomicAdd(&lfill[b], 1);
        int idx = loff[b] + lp;
        pairs[idx] = make_uint2((uint)s2, (uint)d);
        gd[idx] = (uint)(gpos[b] + lp);
    }
    __syncthreads();
    for (int i = t; i < n; i += 256)
        ebuf[gd[i]] = pairs[i];                 // coalesced runs (~21 edges)
}

// Pass C: per-bucket local CSR (rowptr, colidx, dinv) — one block per bucket.
__global__ __launch_bounds__(256) void k_csr(const uint2* __restrict__ ebuf,
                                             const int* __restrict__ boff,
                                             int* __restrict__ rowptr,
                                             float* __restrict__ dinv,
                                             int* __restrict__ colidx) {
    __shared__ int hist[512];
    __shared__ int lptr[512];
    int t = threadIdx.x;
    int b = blockIdx.x;
    int v0 = b << 9;
    int e0 = boff[b], e1 = boff[b + 1];
    int m = e1 - e0;
    for (int i = t; i < 512; i += 256) hist[i] = 0;
    __syncthreads();
    for (int i = t; i < m; i += 256)
        atomicAdd(&hist[(int)ebuf[e0 + i].y - v0], 1);
    __syncthreads();
    if (t < 64) {                                // wave-0 scan of 512 entries
        int run = 0;
        #pragma unroll
        for (int j = 0; j < 8; ++j) { lptr[8 * t + j] = run; run += hist[8 * t + j]; }
        int inc = run;
        #pragma unroll
        for (int o = 1; o < 64; o <<= 1) {
            int u = __shfl_up(inc, o);
            if (t >= o) inc += u;
        }
        int excl = inc - run;
        #pragma unroll
        for (int j = 0; j < 8; ++j) lptr[8 * t + j] += excl;
    }
    __syncthreads();
    for (int i = t; i < 512; i += 256) {
        int v = v0 + i;
        if (v < N_NODES) {
            rowptr[v] = e0 + lptr[i];
            dinv[v] = rsqrtf((float)(hist[i] + 1));   // +1 self-loop
        }
    }
    __syncthreads();
    for (int i = t; i < 512; i += 256) hist[i] = 0;   // reuse as fill cursor
    __syncthreads();
    for (int i = t; i < m; i += 256) {
        uint2 p = ebuf[e0 + i];
        int lr = (int)p.y - v0;
        int lp = atomicAdd(&hist[lr], 1);
        colidx[e0 + lptr[lr] + lp] = (int)p.x;        // block-private 32KB window
    }
}

// ---------------- GEMM1: h1s = dinv*(x @ W1), bf16x2 packed ----------------
__global__ __launch_bounds__(256) void k_gemm1(const float* __restrict__ x,
                                               const float* __restrict__ W,
                                               const float* __restrict__ dinv,
                                               uint* __restrict__ h1b) {
    __shared__ float Ws[32 * 128];
    int wid = threadIdx.x >> 6, lane = threadIdx.x & 63;
    int r0 = __builtin_amdgcn_readfirstlane(blockIdx.x * 32 + wid * 8);
    float acc0[8] = {}, acc1[8] = {};
    #pragma unroll
    for (int kt = 0; kt < 4; ++kt) {
        __syncthreads();
        {
            const float4* Wg = (const float4*)(W + kt * 32 * 128);
            float4* Wl = (float4*)Ws;
            #pragma unroll
            for (int i = 0; i < 4; ++i) Wl[threadIdx.x + 256 * i] = Wg[threadIdx.x + 256 * i];
        }
        __syncthreads();
        #pragma unroll
        for (int k = 0; k < 32; ++k) {
            float2 wv = ((const float2*)Ws)[k * 64 + lane];
            #pragma unroll
            for (int j = 0; j < 8; ++j) {
                float xk = x[(r0 + j) * 128 + kt * 32 + k];  // uniform -> s_load
                acc0[j] = fmaf(xk, wv.x, acc0[j]);
                acc1[j] = fmaf(xk, wv.y, acc1[j]);
            }
        }
    }
    #pragma unroll
    for (int j = 0; j < 8; ++j) {
        float dv = dinv[r0 + j];                          // uniform -> s_load
        uint pk = bf16_rne(acc0[j] * dv) | (bf16_rne(acc1[j] * dv) << 16);
        h1b[(r0 + j) * 64 + lane] = pk;
    }
}

// ---------------- agg1: out1 = dv*(sum_s h1s[s] + h1s[v]) + b1 ----------------
__global__ __launch_bounds__(256) void k_agg1(const uint* __restrict__ h1b,
                                              const int* __restrict__ rowptr,
                                              const int* __restrict__ colidx,
                                              const float* __restrict__ dinv,
                                              const float* __restrict__ b1,
                                              float* __restrict__ out1) {
    int v = __builtin_amdgcn_readfirstlane(blockIdx.x * 4 + (threadIdx.x >> 6));
    int lane = threadIdx.x & 63;
    if (v >= N_NODES) return;
    int beg = rowptr[v], end = rowptr[v + 1];
    uint us = h1b[v * 64 + lane];                     // self-loop term
    float a0 = bf_lo(us), a1 = bf_hi(us);
    int p = beg;
    for (; p + 4 <= end; p += 4) {
        int s0 = colidx[p], s1 = colidx[p + 1], s2 = colidx[p + 2], s3 = colidx[p + 3];
        uint u0 = h1b[s0 * 64 + lane];
        uint u1 = h1b[s1 * 64 + lane];
        uint u2 = h1b[s2 * 64 + lane];
        uint u3 = h1b[s3 * 64 + lane];
        a0 += bf_lo(u0) + bf_lo(u1) + bf_lo(u2) + bf_lo(u3);
        a1 += bf_hi(u0) + bf_hi(u1) + bf_hi(u2) + bf_hi(u3);
    }
    for (; p < end; ++p) {
        uint u = h1b[colidx[p] * 64 + lane];
        a0 += bf_lo(u);
        a1 += bf_hi(u);
    }
    float dv = dinv[v];
    float2 o;
    o.x = fmaf(dv, a0, b1[2 * lane]);
    o.y = fmaf(dv, a1, b1[2 * lane + 1]);
    ((float2*)out1)[v * 64 + lane] = o;
}

// ---------------- BN stats ----------------
__global__ __launch_bounds__(256) void k_bnstats(const float* __restrict__ out1,
                                                 float* __restrict__ sum,
                                                 float* __restrict__ sumsq) {
    int f = threadIdx.x & 127;
    int n0 = blockIdx.x * 2 + (threadIdx.x >> 7);
    float s = 0.f, ss = 0.f;
    for (int n = n0; n < N_NODES; n += gridDim.x * 2) {
        float v = out1[n * 128 + f];
        s += v;
        ss += v * v;
    }
    __shared__ float ls[256], lss[256];
    ls[threadIdx.x] = s;
    lss[threadIdx.x] = ss;
    __syncthreads();
    if (threadIdx.x < 128) {
        atomicAdd(&sum[f], ls[threadIdx.x] + ls[threadIdx.x + 128]);
        atomicAdd(&sumsq[f], lss[threadIdx.x] + lss[threadIdx.x + 128]);
    }
}

__global__ void k_bnfinal(const float* __restrict__ sum, const float* __restrict__ sumsq,
                          const float* __restrict__ gamma, const float* __restrict__ beta,
                          float* __restrict__ scale, float* __restrict__ shift) {
    int f = threadIdx.x;   // 128 threads
    float mean = sum[f] * (1.f / N_NODES);
    float var = sumsq[f] * (1.f / N_NODES) - mean * mean;
    float rstd = rsqrtf(var + BN_EPS);
    float sc = gamma[f] * rstd;
    scale[f] = sc;
    shift[f] = beta[f] - mean * sc;
}

// ---------------- GEMM2 (BN+ReLU fused on scalar load): h2s = dinv*(relu(bn(out1)) @ W2) ----------------
__global__ __launch_bounds__(256) void k_gemm2(const float* __restrict__ out1,
                                               const float* __restrict__ W2,
                                               const float* __restrict__ scale,
                                               const float* __restrict__ shift,
                                               const float* __restrict__ dinv,
                                               ushort* __restrict__ h2b) {
    __shared__ float W2s[128 * 40 + 64];
    {
        const float4* Wg = (const float4*)W2;
        float4* Wl = (float4*)W2s;
        #pragma unroll
        for (int i = 0; i < 5; ++i) Wl[threadIdx.x + 256 * i] = Wg[threadIdx.x + 256 * i];
    }
    __syncthreads();
    int wid = threadIdx.x >> 6, lane = threadIdx.x & 63;
    int r0 = __builtin_amdgcn_readfirstlane(blockIdx.x * 32 + wid * 8);
    float acc[8] = {};
    #pragma unroll 16
    for (int k = 0; k < 128; ++k) {
        float w = W2s[k * 40 + lane];          // lanes 40-63 read junk, never stored
        float sck = scale[k], shk = shift[k];  // uniform -> s_load
        #pragma unroll
        for (int j = 0; j < 8; ++j) {
            float xk = out1[(r0 + j) * 128 + k];                // uniform -> s_load
            xk = fmaxf(fmaf(xk, sck, shk), 0.f);                // BN + ReLU
            acc[j] = fmaf(xk, w, acc[j]);
        }
    }
    if (lane < F_OUT) {
        #pragma unroll
        for (int j = 0; j < 8; ++j) {
            float dv = dinv[r0 + j];
            h2b[(r0 + j) * F_OUT + lane] = (ushort)bf16_rne(acc[j] * dv);
        }
    }
}

// ---------------- agg2 + b2 + log_softmax ----------------
__global__ __launch_bounds__(256) void k_agg2(const uint* __restrict__ h2u,
                                              const int* __restrict__ rowptr,
                                              const int* __restrict__ colidx,
                                              const float* __restrict__ dinv,
                                              const float* __restrict__ b2,
                                              float* __restrict__ out) {
    int v = __builtin_amdgcn_readfirstlane(blockIdx.x * 4 + (threadIdx.x >> 6));
    int lane = threadIdx.x & 63;
    if (v >= N_NODES) return;
    bool act = lane < 20;
    int li = act ? lane : 0;
    int beg = rowptr[v], end = rowptr[v + 1];
    uint us = act ? h2u[v * 20 + li] : 0u;
    float a0 = bf_lo(us), a1 = bf_hi(us);
    int p = beg;
    for (; p + 4 <= end; p += 4) {
        int s0 = colidx[p], s1 = colidx[p + 1], s2 = colidx[p + 2], s3 = colidx[p + 3];
        uint u0 = act ? h2u[s0 * 20 + li] : 0u;
        uint u1 = act ? h2u[s1 * 20 + li] : 0u;
        uint u2 = act ? h2u[s2 * 20 + li] : 0u;
        uint u3 = act ? h2u[s3 * 20 + li] : 0u;
        a0 += bf_lo(u0) + bf_lo(u1) + bf_lo(u2) + bf_lo(u3);
        a1 += bf_hi(u0) + bf_hi(u1) + bf_hi(u2) + bf_hi(u3);
    }
    for (; p < end; ++p) {
        uint u = act ? h2u[colidx[p] * 20 + li] : 0u;
        a0 += bf_lo(u);
        a1 += bf_hi(u);
    }
    float dv = dinv[v];
    float z0 = act ? fmaf(dv, a0, b2[2 * li])     : -1e30f;
    float z1 = act ? fmaf(dv, a1, b2[2 * li + 1]) : -1e30f;
    float m = fmaxf(z0, z1);
    #pragma unroll
    for (int off = 32; off; off >>= 1) m = fmaxf(m, __shfl_xor(m, off));
    float e = act ? (__expf(z0 - m) + __expf(z1 - m)) : 0.f;
    float ssum = e;
    #pragma unroll
    for (int off = 32; off; off >>= 1) ssum += __shfl_xor(ssum, off);
    float ls = __logf(ssum);
    if (act) {
        float2 o;
        o.x = z0 - m - ls;
        o.y = z1 - m - ls;
        ((float2*)out)[v * 20 + li] = o;
    }
}

// ---------------- launch ----------------
extern "C" void kernel_launch(void* const* d_in, const int* in_sizes, int n_in,
                              void* d_out, int out_size, void* d_ws, size_t ws_size,
                              hipStream_t stream) {
    const float* x     = (const float*)d_in[0];
    const float* W1    = (const float*)d_in[1];
    const float* b1    = (const float*)d_in[2];
    const float* gamma = (const float*)d_in[3];
    const float* beta  = (const float*)d_in[4];
    const float* W2    = (const float*)d_in[5];
    const float* b2    = (const float*)d_in[6];
    const int* esrc    = (const int*)d_in[7];
    const int* edst    = (const int*)d_in[8];
    float* out         = (float*)d_out;

    // workspace layout
    char* w = (char*)d_ws;
    size_t off = 0;
    auto alloc = [&](size_t bytes) -> void* {
        void* p = w + off;
        off = (off + bytes + 255) & ~(size_t)255;
        return p;
    };
    int*   gcnt   = (int*)alloc(256 * 4);
    int*   boff   = (int*)alloc((NBUCK + 1) * 4);
    int*   gfill  = (int*)alloc(NBUCK * 4);
    int*   rowptr = (int*)alloc((N_NODES + 1) * 4);
    float* dinv   = (float*)alloc(N_NODES * 4);
    int*   colidx = (int*)alloc((size_t)N_EDGES * 4);
    uint*  h1b    = (uint*)alloc((size_t)N_NODES * 64 * 4);    // bf16x2 [N,128]
    float* out1   = (float*)alloc((size_t)N_NODES * F_HID * 4);
    float* bnsum  = (float*)alloc(128 * 4);
    float* bnsq   = (float*)alloc(128 * 4);
    float* scale  = (float*)alloc(128 * 4);
    float* shift  = (float*)alloc(128 * 4);
    uint2* ebuf   = (uint2*)h1b;    // 12.8MB, dead before gemm1 writes h1b
    ushort* h2b   = (ushort*)h1b;   // h1b dead after agg1; reuse: bf16 [N,40]

    (void)ws_size; (void)in_sizes; (void)n_in; (void)out_size;

    hipMemsetAsync(gcnt,  0, 256 * 4, stream);
    hipMemsetAsync(bnsum, 0, 128 * 4, stream);
    hipMemsetAsync(bnsq,  0, 128 * 4, stream);

    k_hist <<<NCHUNK, 256, 0, stream>>>(edst, gcnt);
    k_bscan<<<1, 256, 0, stream>>>(gcnt, boff, gfill, rowptr);
    k_part <<<NCHUNK, 256, 0, stream>>>(esrc, edst, gfill, ebuf);
    k_csr  <<<NBUCK, 256, 0, stream>>>(ebuf, boff, rowptr, dinv, colidx);

    k_gemm1<<<N_NODES / 32, 256, 0, stream>>>(x, W1, dinv, h1b);
    k_agg1<<<(N_NODES + 3) / 4, 256, 0, stream>>>(h1b, rowptr, colidx, dinv, b1, out1);

    k_bnstats<<<512, 256, 0, stream>>>(out1, bnsum, bnsq);
    k_bnfinal<<<1, 128, 0, stream>>>(bnsum, bnsq, gamma, beta, scale, shift);

    k_gemm2<<<N_NODES / 32, 256, 0, stream>>>(out1, W2, scale, shift, dinv, h2b);
    k_agg2<<<(N_NODES + 3) / 4, 256, 0, stream>>>((const uint*)h2b, rowptr, colidx, dinv, b2, out);
}

// Round 5
// 378.417 us; speedup vs baseline: 1.5547x; 1.5547x over previous
//
#include <hip/hip_runtime.h>
#include <cstdint>
#include <cstddef>

constexpr int N_NODES = 100000;
constexpr int N_EDGES = 1600000;
constexpr int F_IN   = 128;
constexpr int F_HID  = 128;
constexpr int F_OUT  = 40;
constexpr float BN_EPS = 1e-5f;

constexpr int NBUCK  = 196;      // ceil(100000 / 512), bucket = dst >> 9
constexpr int ECHUNK = 4096;     // edges per partition block
constexpr int NCHUNK = (N_EDGES + ECHUNK - 1) / ECHUNK;   // 391

typedef unsigned int uint;
typedef unsigned short ushort;

// ---------------- helpers ----------------
__device__ inline uint bf16_rne(float f) {
    uint u = __float_as_uint(f);
    return (u + 0x7fffu + ((u >> 16) & 1u)) >> 16;
}
__device__ inline float bf_lo(uint u) { return __uint_as_float(u << 16); }
__device__ inline float bf_hi(uint u) { return __uint_as_float(u & 0xffff0000u); }

// ---------------- CSR build: bucketed two-level ----------------
__global__ __launch_bounds__(256) void k_hist(const int* __restrict__ dst,
                                              int* __restrict__ gcnt) {
    __shared__ int hist[NBUCK];
    for (int i = threadIdx.x; i < NBUCK; i += 256) hist[i] = 0;
    __syncthreads();
    int base = blockIdx.x * ECHUNK;
    int n = min(ECHUNK, N_EDGES - base);
    for (int i = threadIdx.x; i < n; i += 256)
        atomicAdd(&hist[dst[base + i] >> 9], 1);
    __syncthreads();
    for (int i = threadIdx.x; i < NBUCK; i += 256)
        if (hist[i]) atomicAdd(&gcnt[i], hist[i]);
}

__global__ void k_bscan(const int* __restrict__ gcnt, int* __restrict__ boff,
                        int* __restrict__ gfill, int* __restrict__ rowptr) {
    __shared__ int s[256];
    int t = threadIdx.x;
    int c = (t < NBUCK) ? gcnt[t] : 0;
    s[t] = c;
    __syncthreads();
    #pragma unroll
    for (int o = 1; o < 256; o <<= 1) {
        int v = (t >= o) ? s[t - o] : 0;
        __syncthreads();
        s[t] += v;
        __syncthreads();
    }
    if (t < NBUCK) { int e = s[t] - c; boff[t] = e; gfill[t] = e; }
    if (t == 0) { boff[NBUCK] = N_EDGES; rowptr[N_NODES] = N_EDGES; }
}

__global__ __launch_bounds__(256) void k_part(const int* __restrict__ src,
                                              const int* __restrict__ dst,
                                              int* __restrict__ gfill,
                                              uint2* __restrict__ ebuf) {
    __shared__ uint2 pairs[ECHUNK];          // 32 KB
    __shared__ uint  gd[ECHUNK];             // 16 KB
    __shared__ int hist[NBUCK], loff[NBUCK], gpos[NBUCK], lfill[NBUCK];
    __shared__ int sc[256];
    int t = threadIdx.x;
    for (int i = t; i < NBUCK; i += 256) { hist[i] = 0; lfill[i] = 0; }
    __syncthreads();
    int base = blockIdx.x * ECHUNK;
    int n = min(ECHUNK, N_EDGES - base);
    for (int i = t; i < n; i += 256)
        atomicAdd(&hist[dst[base + i] >> 9], 1);
    __syncthreads();
    int c = (t < NBUCK) ? hist[t] : 0;
    sc[t] = c;
    __syncthreads();
    #pragma unroll
    for (int o = 1; o < 256; o <<= 1) {
        int v = (t >= o) ? sc[t - o] : 0;
        __syncthreads();
        sc[t] += v;
        __syncthreads();
    }
    if (t < NBUCK) {
        loff[t] = sc[t] - c;
        gpos[t] = c ? atomicAdd(&gfill[t], c) : 0;
    }
    __syncthreads();
    for (int i = t; i < n; i += 256) {
        int d = dst[base + i];
        int s2 = src[base + i];
        int b = d >> 9;
        int lp = atomicAdd(&lfill[b], 1);
        int idx = loff[b] + lp;
        pairs[idx] = make_uint2((uint)s2, (uint)d);
        gd[idx] = (uint)(gpos[b] + lp);
    }
    __syncthreads();
    for (int i = t; i < n; i += 256)
        ebuf[gd[i]] = pairs[i];                 // coalesced runs (~21 edges)
}

__global__ __launch_bounds__(256) void k_csr(const uint2* __restrict__ ebuf,
                                             const int* __restrict__ boff,
                                             int* __restrict__ rowptr,
                                             float* __restrict__ dinv,
                                             int* __restrict__ colidx) {
    __shared__ int hist[512];
    __shared__ int lptr[512];
    int t = threadIdx.x;
    int b = blockIdx.x;
    int v0 = b << 9;
    int e0 = boff[b], e1 = boff[b + 1];
    int m = e1 - e0;
    for (int i = t; i < 512; i += 256) hist[i] = 0;
    __syncthreads();
    for (int i = t; i < m; i += 256)
        atomicAdd(&hist[(int)ebuf[e0 + i].y - v0], 1);
    __syncthreads();
    if (t < 64) {                                // wave-0 scan of 512 entries
        int run = 0;
        #pragma unroll
        for (int j = 0; j < 8; ++j) { lptr[8 * t + j] = run; run += hist[8 * t + j]; }
        int inc = run;
        #pragma unroll
        for (int o = 1; o < 64; o <<= 1) {
            int u = __shfl_up(inc, o);
            if (t >= o) inc += u;
        }
        int excl = inc - run;
        #pragma unroll
        for (int j = 0; j < 8; ++j) lptr[8 * t + j] += excl;
    }
    __syncthreads();
    for (int i = t; i < 512; i += 256) {
        int v = v0 + i;
        if (v < N_NODES) {
            rowptr[v] = e0 + lptr[i];
            dinv[v] = rsqrtf((float)(hist[i] + 1));   // +1 self-loop
        }
    }
    __syncthreads();
    for (int i = t; i < 512; i += 256) hist[i] = 0;   // reuse as fill cursor
    __syncthreads();
    for (int i = t; i < m; i += 256) {
        uint2 p = ebuf[e0 + i];
        int lr = (int)p.y - v0;
        int lp = atomicAdd(&hist[lr], 1);
        colidx[e0 + lptr[lr] + lp] = (int)p.x;        // block-private 32KB window
    }
}

// ---------------- GEMM1: h1s = dinv*(x @ W1), bf16x2 packed ----------------
__global__ __launch_bounds__(256) void k_gemm1(const float* __restrict__ x,
                                               const float* __restrict__ W,
                                               const float* __restrict__ dinv,
                                               uint* __restrict__ h1b) {
    __shared__ float Ws[32 * 128];
    int wid = threadIdx.x >> 6, lane = threadIdx.x & 63;
    int r0 = __builtin_amdgcn_readfirstlane(blockIdx.x * 32 + wid * 8);
    float acc0[8] = {}, acc1[8] = {};
    #pragma unroll
    for (int kt = 0; kt < 4; ++kt) {
        __syncthreads();
        {
            const float4* Wg = (const float4*)(W + kt * 32 * 128);
            float4* Wl = (float4*)Ws;
            #pragma unroll
            for (int i = 0; i < 4; ++i) Wl[threadIdx.x + 256 * i] = Wg[threadIdx.x + 256 * i];
        }
        __syncthreads();
        #pragma unroll
        for (int k = 0; k < 32; ++k) {
            float2 wv = ((const float2*)Ws)[k * 64 + lane];
            #pragma unroll
            for (int j = 0; j < 8; ++j) {
                float xk = x[(r0 + j) * 128 + kt * 32 + k];  // uniform -> s_load
                acc0[j] = fmaf(xk, wv.x, acc0[j]);
                acc1[j] = fmaf(xk, wv.y, acc1[j]);
            }
        }
    }
    #pragma unroll
    for (int j = 0; j < 8; ++j) {
        float dv = dinv[r0 + j];                          // uniform -> s_load
        uint pk = bf16_rne(acc0[j] * dv) | (bf16_rne(acc1[j] * dv) << 16);
        h1b[(r0 + j) * 64 + lane] = pk;
    }
}

// ---------------- agg1: out1 = dv*(sum_s h1s[s] + h1s[v]) + b1 ----------------
__global__ __launch_bounds__(256) void k_agg1(const uint* __restrict__ h1b,
                                              const int* __restrict__ rowptr,
                                              const int* __restrict__ colidx,
                                              const float* __restrict__ dinv,
                                              const float* __restrict__ b1,
                                              float* __restrict__ out1) {
    int v = __builtin_amdgcn_readfirstlane(blockIdx.x * 4 + (threadIdx.x >> 6));
    int lane = threadIdx.x & 63;
    if (v >= N_NODES) return;
    int beg = rowptr[v], end = rowptr[v + 1];
    uint us = h1b[v * 64 + lane];                     // self-loop term
    float a0 = bf_lo(us), a1 = bf_hi(us);
    int p = beg;
    for (; p + 4 <= end; p += 4) {
        int s0 = colidx[p], s1 = colidx[p + 1], s2 = colidx[p + 2], s3 = colidx[p + 3];
        uint u0 = h1b[s0 * 64 + lane];
        uint u1 = h1b[s1 * 64 + lane];
        uint u2 = h1b[s2 * 64 + lane];
        uint u3 = h1b[s3 * 64 + lane];
        a0 += bf_lo(u0) + bf_lo(u1) + bf_lo(u2) + bf_lo(u3);
        a1 += bf_hi(u0) + bf_hi(u1) + bf_hi(u2) + bf_hi(u3);
    }
    for (; p < end; ++p) {
        uint u = h1b[colidx[p] * 64 + lane];
        a0 += bf_lo(u);
        a1 += bf_hi(u);
    }
    float dv = dinv[v];
    float2 o;
    o.x = fmaf(dv, a0, b1[2 * lane]);
    o.y = fmaf(dv, a1, b1[2 * lane + 1]);
    ((float2*)out1)[v * 64 + lane] = o;
}

// ---------------- BN stats ----------------
__global__ __launch_bounds__(256) void k_bnstats(const float* __restrict__ out1,
                                                 float* __restrict__ sum,
                                                 float* __restrict__ sumsq) {
    int f = threadIdx.x & 127;
    int n0 = blockIdx.x * 2 + (threadIdx.x >> 7);
    float s = 0.f, ss = 0.f;
    for (int n = n0; n < N_NODES; n += gridDim.x * 2) {
        float v = out1[n * 128 + f];
        s += v;
        ss += v * v;
    }
    __shared__ float ls[256], lss[256];
    ls[threadIdx.x] = s;
    lss[threadIdx.x] = ss;
    __syncthreads();
    if (threadIdx.x < 128) {
        atomicAdd(&sum[f], ls[threadIdx.x] + ls[threadIdx.x + 128]);
        atomicAdd(&sumsq[f], lss[threadIdx.x] + lss[threadIdx.x + 128]);
    }
}

__global__ void k_bnfinal(const float* __restrict__ sum, const float* __restrict__ sumsq,
                          const float* __restrict__ gamma, const float* __restrict__ beta,
                          float* __restrict__ scale, float* __restrict__ shift) {
    int f = threadIdx.x;   // 128 threads
    float mean = sum[f] * (1.f / N_NODES);
    float var = sumsq[f] * (1.f / N_NODES) - mean * mean;
    float rstd = rsqrtf(var + BN_EPS);
    float sc = gamma[f] * rstd;
    scale[f] = sc;
    shift[f] = beta[f] - mean * sc;
}

// ---------------- BN apply + ReLU -> bf16x2 packed out1b ----------------
__global__ __launch_bounds__(256) void k_bnapply2(const float* __restrict__ out1,
                                                  const float* __restrict__ scale,
                                                  const float* __restrict__ shift,
                                                  uint* __restrict__ out1b) {
    int i = blockIdx.x * 256 + threadIdx.x;        // float4 index
    float4 v = ((const float4*)out1)[i];
    float4 sc = ((const float4*)scale)[i & 31];
    float4 sh = ((const float4*)shift)[i & 31];
    v.x = fmaxf(fmaf(v.x, sc.x, sh.x), 0.f);
    v.y = fmaxf(fmaf(v.y, sc.y, sh.y), 0.f);
    v.z = fmaxf(fmaf(v.z, sc.z, sh.z), 0.f);
    v.w = fmaxf(fmaf(v.w, sc.w, sh.w), 0.f);
    uint2 o;
    o.x = bf16_rne(v.x) | (bf16_rne(v.y) << 16);
    o.y = bf16_rne(v.z) | (bf16_rne(v.w) << 16);
    ((uint2*)out1b)[i] = o;
}

// ---------------- GEMM2: h2s = dinv*(out1b @ W2), bf16 in, bf16 out ----------------
// Wave owns 8 rows; lane (<40) owns one output col. Operand via wave-uniform
// s_load of packed uint; unpack on SALU (s_lshl/s_and); pure v_fmac on VALU.
__global__ __launch_bounds__(256) void k_gemm2(const uint* __restrict__ out1b,
                                               const float* __restrict__ W2,
                                               const float* __restrict__ dinv,
                                               ushort* __restrict__ h2b) {
    __shared__ float W2s[128 * 40 + 64];
    {
        const float4* Wg = (const float4*)W2;
        float4* Wl = (float4*)W2s;
        #pragma unroll
        for (int i = 0; i < 5; ++i) Wl[threadIdx.x + 256 * i] = Wg[threadIdx.x + 256 * i];
    }
    __syncthreads();
    int wid = threadIdx.x >> 6, lane = threadIdx.x & 63;
    int r0 = __builtin_amdgcn_readfirstlane(blockIdx.x * 32 + wid * 8);
    float acc[8] = {};
    #pragma unroll 8
    for (int k2 = 0; k2 < 64; ++k2) {
        float w0 = W2s[(2 * k2) * 40 + lane];       // lanes 40-63: junk, unused
        float w1 = W2s[(2 * k2 + 1) * 40 + lane];
        #pragma unroll
        for (int j = 0; j < 8; ++j) {
            uint u = out1b[(r0 + j) * 64 + k2];     // uniform -> s_load
            acc[j] = fmaf(bf_lo(u), w0, acc[j]);
            acc[j] = fmaf(bf_hi(u), w1, acc[j]);
        }
    }
    if (lane < F_OUT) {
        #pragma unroll
        for (int j = 0; j < 8; ++j) {
            float dv = dinv[r0 + j];
            h2b[(r0 + j) * F_OUT + lane] = (ushort)bf16_rne(acc[j] * dv);
        }
    }
}

// ---------------- agg2 + b2 + log_softmax ----------------
__global__ __launch_bounds__(256) void k_agg2(const uint* __restrict__ h2u,
                                              const int* __restrict__ rowptr,
                                              const int* __restrict__ colidx,
                                              const float* __restrict__ dinv,
                                              const float* __restrict__ b2,
                                              float* __restrict__ out) {
    int v = __builtin_amdgcn_readfirstlane(blockIdx.x * 4 + (threadIdx.x >> 6));
    int lane = threadIdx.x & 63;
    if (v >= N_NODES) return;
    bool act = lane < 20;
    int li = act ? lane : 0;
    int beg = rowptr[v], end = rowptr[v + 1];
    uint us = act ? h2u[v * 20 + li] : 0u;
    float a0 = bf_lo(us), a1 = bf_hi(us);
    int p = beg;
    for (; p + 4 <= end; p += 4) {
        int s0 = colidx[p], s1 = colidx[p + 1], s2 = colidx[p + 2], s3 = colidx[p + 3];
        uint u0 = act ? h2u[s0 * 20 + li] : 0u;
        uint u1 = act ? h2u[s1 * 20 + li] : 0u;
        uint u2 = act ? h2u[s2 * 20 + li] : 0u;
        uint u3 = act ? h2u[s3 * 20 + li] : 0u;
        a0 += bf_lo(u0) + bf_lo(u1) + bf_lo(u2) + bf_lo(u3);
        a1 += bf_hi(u0) + bf_hi(u1) + bf_hi(u2) + bf_hi(u3);
    }
    for (; p < end; ++p) {
        uint u = act ? h2u[colidx[p] * 20 + li] : 0u;
        a0 += bf_lo(u);
        a1 += bf_hi(u);
    }
    float dv = dinv[v];
    float z0 = act ? fmaf(dv, a0, b2[2 * li])     : -1e30f;
    float z1 = act ? fmaf(dv, a1, b2[2 * li + 1]) : -1e30f;
    float m = fmaxf(z0, z1);
    #pragma unroll
    for (int off = 32; off; off >>= 1) m = fmaxf(m, __shfl_xor(m, off));
    float e = act ? (__expf(z0 - m) + __expf(z1 - m)) : 0.f;
    float ssum = e;
    #pragma unroll
    for (int off = 32; off; off >>= 1) ssum += __shfl_xor(ssum, off);
    float ls = __logf(ssum);
    if (act) {
        float2 o;
        o.x = z0 - m - ls;
        o.y = z1 - m - ls;
        ((float2*)out)[v * 20 + li] = o;
    }
}

// ---------------- launch ----------------
extern "C" void kernel_launch(void* const* d_in, const int* in_sizes, int n_in,
                              void* d_out, int out_size, void* d_ws, size_t ws_size,
                              hipStream_t stream) {
    const float* x     = (const float*)d_in[0];
    const float* W1    = (const float*)d_in[1];
    const float* b1    = (const float*)d_in[2];
    const float* gamma = (const float*)d_in[3];
    const float* beta  = (const float*)d_in[4];
    const float* W2    = (const float*)d_in[5];
    const float* b2    = (const float*)d_in[6];
    const int* esrc    = (const int*)d_in[7];
    const int* edst    = (const int*)d_in[8];
    float* out         = (float*)d_out;

    // workspace layout
    char* w = (char*)d_ws;
    size_t off = 0;
    auto alloc = [&](size_t bytes) -> void* {
        void* p = w + off;
        off = (off + bytes + 255) & ~(size_t)255;
        return p;
    };
    int*   gcnt   = (int*)alloc(256 * 4);
    int*   boff   = (int*)alloc((NBUCK + 1) * 4);
    int*   gfill  = (int*)alloc(NBUCK * 4);
    int*   rowptr = (int*)alloc((N_NODES + 1) * 4);
    float* dinv   = (float*)alloc(N_NODES * 4);
    int*   colidx = (int*)alloc((size_t)N_EDGES * 4);
    uint*  h1b    = (uint*)alloc((size_t)N_NODES * 64 * 4);    // bf16x2 [N,128]
    float* out1   = (float*)alloc((size_t)N_NODES * F_HID * 4);
    ushort* h2b   = (ushort*)alloc((size_t)N_NODES * F_OUT * 2); // bf16 [N,40]
    float* bnsum  = (float*)alloc(128 * 4);
    float* bnsq   = (float*)alloc(128 * 4);
    float* scale  = (float*)alloc(128 * 4);
    float* shift  = (float*)alloc(128 * 4);
    uint2* ebuf   = (uint2*)h1b;    // 12.8MB, dead before gemm1 writes h1b
    uint*  out1b  = h1b;            // h1b dead after agg1; reuse: bf16x2 [N,128]

    (void)ws_size; (void)in_sizes; (void)n_in; (void)out_size;

    hipMemsetAsync(gcnt,  0, 256 * 4, stream);
    hipMemsetAsync(bnsum, 0, 128 * 4, stream);
    hipMemsetAsync(bnsq,  0, 128 * 4, stream);

    k_hist <<<NCHUNK, 256, 0, stream>>>(edst, gcnt);
    k_bscan<<<1, 256, 0, stream>>>(gcnt, boff, gfill, rowptr);
    k_part <<<NCHUNK, 256, 0, stream>>>(esrc, edst, gfill, ebuf);
    k_csr  <<<NBUCK, 256, 0, stream>>>(ebuf, boff, rowptr, dinv, colidx);

    k_gemm1<<<N_NODES / 32, 256, 0, stream>>>(x, W1, dinv, h1b);
    k_agg1<<<(N_NODES + 3) / 4, 256, 0, stream>>>(h1b, rowptr, colidx, dinv, b1, out1);

    k_bnstats<<<512, 256, 0, stream>>>(out1, bnsum, bnsq);
    k_bnfinal<<<1, 128, 0, stream>>>(bnsum, bnsq, gamma, beta, scale, shift);
    k_bnapply2<<<N_NODES * F_HID / 4 / 256, 256, 0, stream>>>(out1, scale, shift, out1b);

    k_gemm2<<<N_NODES / 32, 256, 0, stream>>>(out1b, W2, dinv, h2b);
    k_agg2<<<(N_NODES + 3) / 4, 256, 0, stream>>>((const uint*)h2b, rowptr, colidx, dinv, b2, out);
}

// Round 6
// 367.840 us; speedup vs baseline: 1.5994x; 1.0288x over previous
//
#include <hip/hip_runtime.h>
#include <cstdint>
#include <cstddef>

constexpr int N_NODES = 100000;
constexpr int N_EDGES = 1600000;
constexpr int F_IN   = 128;
constexpr int F_HID  = 128;
constexpr int F_OUT  = 40;
constexpr float BN_EPS = 1e-5f;

constexpr int NBUCK  = 196;      // ceil(100000 / 512), bucket = dst >> 9
constexpr int ECHUNK = 4096;     // edges per partition block
constexpr int NCHUNK = (N_EDGES + ECHUNK - 1) / ECHUNK;   // 391

typedef unsigned int uint;
typedef unsigned short ushort;

// ---------------- helpers ----------------
__device__ inline uint bf16_rne(float f) {
    uint u = __float_as_uint(f);
    return (u + 0x7fffu + ((u >> 16) & 1u)) >> 16;
}
__device__ inline float bf_lo(uint u) { return __uint_as_float(u << 16); }
__device__ inline float bf_hi(uint u) { return __uint_as_float(u & 0xffff0000u); }

// ---------------- CSR build: bucketed two-level ----------------
__global__ __launch_bounds__(256) void k_hist(const int* __restrict__ dst,
                                              int* __restrict__ gcnt) {
    __shared__ int hist[NBUCK];
    for (int i = threadIdx.x; i < NBUCK; i += 256) hist[i] = 0;
    __syncthreads();
    int base = blockIdx.x * ECHUNK;
    int n = min(ECHUNK, N_EDGES - base);
    for (int i = threadIdx.x; i < n; i += 256)
        atomicAdd(&hist[dst[base + i] >> 9], 1);
    __syncthreads();
    for (int i = threadIdx.x; i < NBUCK; i += 256)
        if (hist[i]) atomicAdd(&gcnt[i], hist[i]);
}

__global__ void k_bscan(const int* __restrict__ gcnt, int* __restrict__ boff,
                        int* __restrict__ gfill, int* __restrict__ rowptr) {
    __shared__ int s[256];
    int t = threadIdx.x;
    int c = (t < NBUCK) ? gcnt[t] : 0;
    s[t] = c;
    __syncthreads();
    #pragma unroll
    for (int o = 1; o < 256; o <<= 1) {
        int v = (t >= o) ? s[t - o] : 0;
        __syncthreads();
        s[t] += v;
        __syncthreads();
    }
    if (t < NBUCK) { int e = s[t] - c; boff[t] = e; gfill[t] = e; }
    if (t == 0) { boff[NBUCK] = N_EDGES; rowptr[N_NODES] = N_EDGES; }
}

__global__ __launch_bounds__(256) void k_part(const int* __restrict__ src,
                                              const int* __restrict__ dst,
                                              int* __restrict__ gfill,
                                              uint2* __restrict__ ebuf) {
    __shared__ uint2 pairs[ECHUNK];          // 32 KB
    __shared__ uint  gd[ECHUNK];             // 16 KB
    __shared__ int hist[NBUCK], loff[NBUCK], gpos[NBUCK], lfill[NBUCK];
    __shared__ int sc[256];
    int t = threadIdx.x;
    for (int i = t; i < NBUCK; i += 256) { hist[i] = 0; lfill[i] = 0; }
    __syncthreads();
    int base = blockIdx.x * ECHUNK;
    int n = min(ECHUNK, N_EDGES - base);
    for (int i = t; i < n; i += 256)
        atomicAdd(&hist[dst[base + i] >> 9], 1);
    __syncthreads();
    int c = (t < NBUCK) ? hist[t] : 0;
    sc[t] = c;
    __syncthreads();
    #pragma unroll
    for (int o = 1; o < 256; o <<= 1) {
        int v = (t >= o) ? sc[t - o] : 0;
        __syncthreads();
        sc[t] += v;
        __syncthreads();
    }
    if (t < NBUCK) {
        loff[t] = sc[t] - c;
        gpos[t] = c ? atomicAdd(&gfill[t], c) : 0;
    }
    __syncthreads();
    for (int i = t; i < n; i += 256) {
        int d = dst[base + i];
        int s2 = src[base + i];
        int b = d >> 9;
        int lp = atomicAdd(&lfill[b], 1);
        int idx = loff[b] + lp;
        pairs[idx] = make_uint2((uint)s2, (uint)d);
        gd[idx] = (uint)(gpos[b] + lp);
    }
    __syncthreads();
    for (int i = t; i < n; i += 256)
        ebuf[gd[i]] = pairs[i];                 // coalesced runs (~21 edges)
}

__global__ __launch_bounds__(256) void k_csr(const uint2* __restrict__ ebuf,
                                             const int* __restrict__ boff,
                                             int* __restrict__ rowptr,
                                             float* __restrict__ dinv,
                                             int* __restrict__ colidx) {
    __shared__ int hist[512];
    __shared__ int lptr[512];
    int t = threadIdx.x;
    int b = blockIdx.x;
    int v0 = b << 9;
    int e0 = boff[b], e1 = boff[b + 1];
    int m = e1 - e0;
    for (int i = t; i < 512; i += 256) hist[i] = 0;
    __syncthreads();
    for (int i = t; i < m; i += 256)
        atomicAdd(&hist[(int)ebuf[e0 + i].y - v0], 1);
    __syncthreads();
    if (t < 64) {                                // wave-0 scan of 512 entries
        int run = 0;
        #pragma unroll
        for (int j = 0; j < 8; ++j) { lptr[8 * t + j] = run; run += hist[8 * t + j]; }
        int inc = run;
        #pragma unroll
        for (int o = 1; o < 64; o <<= 1) {
            int u = __shfl_up(inc, o);
            if (t >= o) inc += u;
        }
        int excl = inc - run;
        #pragma unroll
        for (int j = 0; j < 8; ++j) lptr[8 * t + j] += excl;
    }
    __syncthreads();
    for (int i = t; i < 512; i += 256) {
        int v = v0 + i;
        if (v < N_NODES) {
            rowptr[v] = e0 + lptr[i];
            dinv[v] = rsqrtf((float)(hist[i] + 1));   // +1 self-loop
        }
    }
    __syncthreads();
    for (int i = t; i < 512; i += 256) hist[i] = 0;   // reuse as fill cursor
    __syncthreads();
    for (int i = t; i < m; i += 256) {
        uint2 p = ebuf[e0 + i];
        int lr = (int)p.y - v0;
        int lp = atomicAdd(&hist[lr], 1);
        colidx[e0 + lptr[lr] + lp] = (int)p.x;        // block-private 32KB window
    }
}

// ---------------- GEMM1: h1s = dinv*(x @ W1), bf16x2 packed ----------------
__global__ __launch_bounds__(256) void k_gemm1(const float* __restrict__ x,
                                               const float* __restrict__ W,
                                               const float* __restrict__ dinv,
                                               uint* __restrict__ h1b) {
    __shared__ float Ws[32 * 128];
    int wid = threadIdx.x >> 6, lane = threadIdx.x & 63;
    int r0 = __builtin_amdgcn_readfirstlane(blockIdx.x * 32 + wid * 8);
    float acc0[8] = {}, acc1[8] = {};
    #pragma unroll
    for (int kt = 0; kt < 4; ++kt) {
        __syncthreads();
        {
            const float4* Wg = (const float4*)(W + kt * 32 * 128);
            float4* Wl = (float4*)Ws;
            #pragma unroll
            for (int i = 0; i < 4; ++i) Wl[threadIdx.x + 256 * i] = Wg[threadIdx.x + 256 * i];
        }
        __syncthreads();
        #pragma unroll
        for (int k = 0; k < 32; ++k) {
            float2 wv = ((const float2*)Ws)[k * 64 + lane];
            #pragma unroll
            for (int j = 0; j < 8; ++j) {
                float xk = x[(r0 + j) * 128 + kt * 32 + k];  // uniform -> s_load
                acc0[j] = fmaf(xk, wv.x, acc0[j]);
                acc1[j] = fmaf(xk, wv.y, acc1[j]);
            }
        }
    }
    #pragma unroll
    for (int j = 0; j < 8; ++j) {
        float dv = dinv[r0 + j];                          // uniform -> s_load
        uint pk = bf16_rne(acc0[j] * dv) | (bf16_rne(acc1[j] * dv) << 16);
        h1b[(r0 + j) * 64 + lane] = pk;
    }
}

// ---------------- agg1: out1 = dv*(sum_s h1s[s] + h1s[v]) + b1 ----------------
// 8-deep unroll: 16 cache lines in flight per wave.
__global__ __launch_bounds__(256) void k_agg1(const uint* __restrict__ h1b,
                                              const int* __restrict__ rowptr,
                                              const int* __restrict__ colidx,
                                              const float* __restrict__ dinv,
                                              const float* __restrict__ b1,
                                              float* __restrict__ out1) {
    int v = __builtin_amdgcn_readfirstlane(blockIdx.x * 4 + (threadIdx.x >> 6));
    int lane = threadIdx.x & 63;
    if (v >= N_NODES) return;
    int beg = rowptr[v], end = rowptr[v + 1];
    uint us = h1b[v * 64 + lane];                     // self-loop term
    float a0 = bf_lo(us), a1 = bf_hi(us);
    int p = beg;
    for (; p + 8 <= end; p += 8) {
        int s0 = colidx[p],     s1 = colidx[p + 1], s2 = colidx[p + 2], s3 = colidx[p + 3];
        int s4 = colidx[p + 4], s5 = colidx[p + 5], s6 = colidx[p + 6], s7 = colidx[p + 7];
        uint u0 = h1b[s0 * 64 + lane];
        uint u1 = h1b[s1 * 64 + lane];
        uint u2 = h1b[s2 * 64 + lane];
        uint u3 = h1b[s3 * 64 + lane];
        uint u4 = h1b[s4 * 64 + lane];
        uint u5 = h1b[s5 * 64 + lane];
        uint u6 = h1b[s6 * 64 + lane];
        uint u7 = h1b[s7 * 64 + lane];
        a0 += bf_lo(u0) + bf_lo(u1) + bf_lo(u2) + bf_lo(u3)
            + bf_lo(u4) + bf_lo(u5) + bf_lo(u6) + bf_lo(u7);
        a1 += bf_hi(u0) + bf_hi(u1) + bf_hi(u2) + bf_hi(u3)
            + bf_hi(u4) + bf_hi(u5) + bf_hi(u6) + bf_hi(u7);
    }
    for (; p < end; ++p) {
        uint u = h1b[colidx[p] * 64 + lane];
        a0 += bf_lo(u);
        a1 += bf_hi(u);
    }
    float dv = dinv[v];
    float2 o;
    o.x = fmaf(dv, a0, b1[2 * lane]);
    o.y = fmaf(dv, a1, b1[2 * lane + 1]);
    ((float2*)out1)[v * 64 + lane] = o;
}

// ---------------- BN stats ----------------
__global__ __launch_bounds__(256) void k_bnstats(const float* __restrict__ out1,
                                                 float* __restrict__ sum,
                                                 float* __restrict__ sumsq) {
    int f = threadIdx.x & 127;
    int n0 = blockIdx.x * 2 + (threadIdx.x >> 7);
    float s = 0.f, ss = 0.f;
    for (int n = n0; n < N_NODES; n += gridDim.x * 2) {
        float v = out1[n * 128 + f];
        s += v;
        ss += v * v;
    }
    __shared__ float ls[256], lss[256];
    ls[threadIdx.x] = s;
    lss[threadIdx.x] = ss;
    __syncthreads();
    if (threadIdx.x < 128) {
        atomicAdd(&sum[f], ls[threadIdx.x] + ls[threadIdx.x + 128]);
        atomicAdd(&sumsq[f], lss[threadIdx.x] + lss[threadIdx.x + 128]);
    }
}

__global__ void k_bnfinal(const float* __restrict__ sum, const float* __restrict__ sumsq,
                          const float* __restrict__ gamma, const float* __restrict__ beta,
                          float* __restrict__ scale, float* __restrict__ shift) {
    int f = threadIdx.x;   // 128 threads
    float mean = sum[f] * (1.f / N_NODES);
    float var = sumsq[f] * (1.f / N_NODES) - mean * mean;
    float rstd = rsqrtf(var + BN_EPS);
    float sc = gamma[f] * rstd;
    scale[f] = sc;
    shift[f] = beta[f] - mean * sc;
}

// ---------------- BN apply + ReLU -> bf16x2 packed out1b ----------------
__global__ __launch_bounds__(256) void k_bnapply2(const float* __restrict__ out1,
                                                  const float* __restrict__ scale,
                                                  const float* __restrict__ shift,
                                                  uint* __restrict__ out1b) {
    int i = blockIdx.x * 256 + threadIdx.x;        // float4 index
    float4 v = ((const float4*)out1)[i];
    float4 sc = ((const float4*)scale)[i & 31];
    float4 sh = ((const float4*)shift)[i & 31];
    v.x = fmaxf(fmaf(v.x, sc.x, sh.x), 0.f);
    v.y = fmaxf(fmaf(v.y, sc.y, sh.y), 0.f);
    v.z = fmaxf(fmaf(v.z, sc.z, sh.z), 0.f);
    v.w = fmaxf(fmaf(v.w, sc.w, sh.w), 0.f);
    uint2 o;
    o.x = bf16_rne(v.x) | (bf16_rne(v.y) << 16);
    o.y = bf16_rne(v.z) | (bf16_rne(v.w) << 16);
    ((uint2*)out1b)[i] = o;
}

// ---------------- GEMM2: h2s = dinv*(out1b @ W2), bf16 in, bf16 out ----------------
__global__ __launch_bounds__(256) void k_gemm2(const uint* __restrict__ out1b,
                                               const float* __restrict__ W2,
                                               const float* __restrict__ dinv,
                                               ushort* __restrict__ h2b) {
    __shared__ float W2s[128 * 40 + 64];
    {
        const float4* Wg = (const float4*)W2;
        float4* Wl = (float4*)W2s;
        #pragma unroll
        for (int i = 0; i < 5; ++i) Wl[threadIdx.x + 256 * i] = Wg[threadIdx.x + 256 * i];
    }
    __syncthreads();
    int wid = threadIdx.x >> 6, lane = threadIdx.x & 63;
    int r0 = __builtin_amdgcn_readfirstlane(blockIdx.x * 32 + wid * 8);
    float acc[8] = {};
    #pragma unroll 8
    for (int k2 = 0; k2 < 64; ++k2) {
        float w0 = W2s[(2 * k2) * 40 + lane];       // lanes 40-63: junk, unused
        float w1 = W2s[(2 * k2 + 1) * 40 + lane];
        #pragma unroll
        for (int j = 0; j < 8; ++j) {
            uint u = out1b[(r0 + j) * 64 + k2];     // uniform -> s_load
            acc[j] = fmaf(bf_lo(u), w0, acc[j]);
            acc[j] = fmaf(bf_hi(u), w1, acc[j]);
        }
    }
    if (lane < F_OUT) {
        #pragma unroll
        for (int j = 0; j < 8; ++j) {
            float dv = dinv[r0 + j];
            h2b[(r0 + j) * F_OUT + lane] = (ushort)bf16_rne(acc[j] * dv);
        }
    }
}

// ---------------- agg2 + b2 + log_softmax ----------------
// Dual-half-wave: lanes 0-31 take even edges, lanes 32-63 odd edges; lane&31
// in [0,20) owns feature pair. 8 gather rows in flight per wave.
__global__ __launch_bounds__(256) void k_agg2(const uint* __restrict__ h2u,
                                              const int* __restrict__ rowptr,
                                              const int* __restrict__ colidx,
                                              const float* __restrict__ dinv,
                                              const float* __restrict__ b2,
                                              float* __restrict__ out) {
    int v = __builtin_amdgcn_readfirstlane(blockIdx.x * 4 + (threadIdx.x >> 6));
    int lane = threadIdx.x & 63;
    if (v >= N_NODES) return;
    int half = lane >> 5;
    int li = lane & 31;
    bool act = li < 20;
    int col = act ? li : 0;
    int beg = rowptr[v], end = rowptr[v + 1];
    float a0 = 0.f, a1 = 0.f;
    int p = beg + half;
    for (; p + 8 <= end; p += 8) {      // 4 edges per half per iteration
        int s0 = colidx[p], s1 = colidx[p + 2], s2 = colidx[p + 4], s3 = colidx[p + 6];
        uint u0 = act ? h2u[s0 * 20 + col] : 0u;
        uint u1 = act ? h2u[s1 * 20 + col] : 0u;
        uint u2 = act ? h2u[s2 * 20 + col] : 0u;
        uint u3 = act ? h2u[s3 * 20 + col] : 0u;
        a0 += bf_lo(u0) + bf_lo(u1) + bf_lo(u2) + bf_lo(u3);
        a1 += bf_hi(u0) + bf_hi(u1) + bf_hi(u2) + bf_hi(u3);
    }
    for (; p < end; p += 2) {
        uint u = act ? h2u[colidx[p] * 20 + col] : 0u;
        a0 += bf_lo(u);
        a1 += bf_hi(u);
    }
    if (half == 0) {                    // self-loop term once
        uint us = act ? h2u[v * 20 + col] : 0u;
        a0 += bf_lo(us);
        a1 += bf_hi(us);
    }
    a0 += __shfl_xor(a0, 32);           // combine halves
    a1 += __shfl_xor(a1, 32);
    float dv = dinv[v];
    bool lead = act && (half == 0);
    float z0 = lead ? fmaf(dv, a0, b2[2 * col])     : -1e30f;
    float z1 = lead ? fmaf(dv, a1, b2[2 * col + 1]) : -1e30f;
    float m = fmaxf(z0, z1);
    #pragma unroll
    for (int off = 32; off; off >>= 1) m = fmaxf(m, __shfl_xor(m, off));
    float e = lead ? (__expf(z0 - m) + __expf(z1 - m)) : 0.f;
    float ssum = e;
    #pragma unroll
    for (int off = 32; off; off >>= 1) ssum += __shfl_xor(ssum, off);
    float ls = __logf(ssum);
    if (lead) {
        float2 o;
        o.x = z0 - m - ls;
        o.y = z1 - m - ls;
        ((float2*)out)[v * 20 + col] = o;
    }
}

// ---------------- launch ----------------
extern "C" void kernel_launch(void* const* d_in, const int* in_sizes, int n_in,
                              void* d_out, int out_size, void* d_ws, size_t ws_size,
                              hipStream_t stream) {
    const float* x     = (const float*)d_in[0];
    const float* W1    = (const float*)d_in[1];
    const float* b1    = (const float*)d_in[2];
    const float* gamma = (const float*)d_in[3];
    const float* beta  = (const float*)d_in[4];
    const float* W2    = (const float*)d_in[5];
    const float* b2    = (const float*)d_in[6];
    const int* esrc    = (const int*)d_in[7];
    const int* edst    = (const int*)d_in[8];
    float* out         = (float*)d_out;

    // workspace layout
    char* w = (char*)d_ws;
    size_t off = 0;
    auto alloc = [&](size_t bytes) -> void* {
        void* p = w + off;
        off = (off + bytes + 255) & ~(size_t)255;
        return p;
    };
    int*   gcnt   = (int*)alloc(256 * 4);
    int*   boff   = (int*)alloc((NBUCK + 1) * 4);
    int*   gfill  = (int*)alloc(NBUCK * 4);
    int*   rowptr = (int*)alloc((N_NODES + 1) * 4);
    float* dinv   = (float*)alloc(N_NODES * 4);
    int*   colidx = (int*)alloc((size_t)N_EDGES * 4);
    uint*  h1b    = (uint*)alloc((size_t)N_NODES * 64 * 4);    // bf16x2 [N,128]
    float* out1   = (float*)alloc((size_t)N_NODES * F_HID * 4);
    ushort* h2b   = (ushort*)alloc((size_t)N_NODES * F_OUT * 2); // bf16 [N,40]
    float* bnsum  = (float*)alloc(128 * 4);
    float* bnsq   = (float*)alloc(128 * 4);
    float* scale  = (float*)alloc(128 * 4);
    float* shift  = (float*)alloc(128 * 4);
    uint2* ebuf   = (uint2*)h1b;    // 12.8MB, dead before gemm1 writes h1b
    uint*  out1b  = h1b;            // h1b dead after agg1; reuse: bf16x2 [N,128]

    (void)ws_size; (void)in_sizes; (void)n_in; (void)out_size;

    hipMemsetAsync(gcnt,  0, 256 * 4, stream);
    hipMemsetAsync(bnsum, 0, 128 * 4, stream);
    hipMemsetAsync(bnsq,  0, 128 * 4, stream);

    k_hist <<<NCHUNK, 256, 0, stream>>>(edst, gcnt);
    k_bscan<<<1, 256, 0, stream>>>(gcnt, boff, gfill, rowptr);
    k_part <<<NCHUNK, 256, 0, stream>>>(esrc, edst, gfill, ebuf);
    k_csr  <<<NBUCK, 256, 0, stream>>>(ebuf, boff, rowptr, dinv, colidx);

    k_gemm1<<<N_NODES / 32, 256, 0, stream>>>(x, W1, dinv, h1b);
    k_agg1<<<(N_NODES + 3) / 4, 256, 0, stream>>>(h1b, rowptr, colidx, dinv, b1, out1);

    k_bnstats<<<512, 256, 0, stream>>>(out1, bnsum, bnsq);
    k_bnfinal<<<1, 128, 0, stream>>>(bnsum, bnsq, gamma, beta, scale, shift);
    k_bnapply2<<<N_NODES * F_HID / 4 / 256, 256, 0, stream>>>(out1, scale, shift, out1b);

    k_gemm2<<<N_NODES / 32, 256, 0, stream>>>(out1b, W2, dinv, h2b);
    k_agg2<<<(N_NODES + 3) / 4, 256, 0, stream>>>((const uint*)h2b, rowptr, colidx, dinv, b2, out);
}

// Round 7
// 344.419 us; speedup vs baseline: 1.7081x; 1.0680x over previous
//
#include <hip/hip_runtime.h>
#include <cstdint>
#include <cstddef>

constexpr int N_NODES = 100000;
constexpr int N_EDGES = 1600000;
constexpr int F_IN   = 128;
constexpr int F_HID  = 128;
constexpr int F_OUT  = 40;
constexpr float BN_EPS = 1e-5f;

constexpr int NBUCK  = 196;      // ceil(100000 / 512), bucket = dst >> 9
constexpr int ECHUNK = 4096;     // edges per partition block
constexpr int NCHUNK = (N_EDGES + ECHUNK - 1) / ECHUNK;   // 391

typedef unsigned int uint;
typedef unsigned short ushort;

// ---------------- helpers ----------------
__device__ inline uint bf16_rne(float f) {
    uint u = __float_as_uint(f);
    return (u + 0x7fffu + ((u >> 16) & 1u)) >> 16;
}
__device__ inline float bf_lo(uint u) { return __uint_as_float(u << 16); }
__device__ inline float bf_hi(uint u) { return __uint_as_float(u & 0xffff0000u); }

// ---------------- CSR build: bucketed two-level ----------------
__global__ __launch_bounds__(256) void k_hist(const int* __restrict__ dst,
                                              int* __restrict__ gcnt) {
    __shared__ int hist[NBUCK];
    for (int i = threadIdx.x; i < NBUCK; i += 256) hist[i] = 0;
    __syncthreads();
    int base = blockIdx.x * ECHUNK;
    int n = min(ECHUNK, N_EDGES - base);
    for (int i = threadIdx.x; i < n; i += 256)
        atomicAdd(&hist[dst[base + i] >> 9], 1);
    __syncthreads();
    for (int i = threadIdx.x; i < NBUCK; i += 256)
        if (hist[i]) atomicAdd(&gcnt[i], hist[i]);
}

__global__ void k_bscan(const int* __restrict__ gcnt, int* __restrict__ boff,
                        int* __restrict__ gfill, int* __restrict__ rowptr) {
    __shared__ int s[256];
    int t = threadIdx.x;
    int c = (t < NBUCK) ? gcnt[t] : 0;
    s[t] = c;
    __syncthreads();
    #pragma unroll
    for (int o = 1; o < 256; o <<= 1) {
        int v = (t >= o) ? s[t - o] : 0;
        __syncthreads();
        s[t] += v;
        __syncthreads();
    }
    if (t < NBUCK) { int e = s[t] - c; boff[t] = e; gfill[t] = e; }
    if (t == 0) { boff[NBUCK] = N_EDGES; rowptr[N_NODES] = N_EDGES; }
}

__global__ __launch_bounds__(256) void k_part(const int* __restrict__ src,
                                              const int* __restrict__ dst,
                                              int* __restrict__ gfill,
                                              uint2* __restrict__ ebuf) {
    __shared__ uint2 pairs[ECHUNK];          // 32 KB
    __shared__ uint  gd[ECHUNK];             // 16 KB
    __shared__ int hist[NBUCK], loff[NBUCK], gpos[NBUCK], lfill[NBUCK];
    __shared__ int sc[256];
    int t = threadIdx.x;
    for (int i = t; i < NBUCK; i += 256) { hist[i] = 0; lfill[i] = 0; }
    __syncthreads();
    int base = blockIdx.x * ECHUNK;
    int n = min(ECHUNK, N_EDGES - base);
    for (int i = t; i < n; i += 256)
        atomicAdd(&hist[dst[base + i] >> 9], 1);
    __syncthreads();
    int c = (t < NBUCK) ? hist[t] : 0;
    sc[t] = c;
    __syncthreads();
    #pragma unroll
    for (int o = 1; o < 256; o <<= 1) {
        int v = (t >= o) ? sc[t - o] : 0;
        __syncthreads();
        sc[t] += v;
        __syncthreads();
    }
    if (t < NBUCK) {
        loff[t] = sc[t] - c;
        gpos[t] = c ? atomicAdd(&gfill[t], c) : 0;
    }
    __syncthreads();
    for (int i = t; i < n; i += 256) {
        int d = dst[base + i];
        int s2 = src[base + i];
        int b = d >> 9;
        int lp = atomicAdd(&lfill[b], 1);
        int idx = loff[b] + lp;
        pairs[idx] = make_uint2((uint)s2, (uint)d);
        gd[idx] = (uint)(gpos[b] + lp);
    }
    __syncthreads();
    for (int i = t; i < n; i += 256)
        ebuf[gd[i]] = pairs[i];                 // coalesced runs (~21 edges)
}

__global__ __launch_bounds__(256) void k_csr(const uint2* __restrict__ ebuf,
                                             const int* __restrict__ boff,
                                             int* __restrict__ rowptr,
                                             float* __restrict__ dinv,
                                             int* __restrict__ colidx) {
    __shared__ int hist[512];
    __shared__ int lptr[512];
    int t = threadIdx.x;
    int b = blockIdx.x;
    int v0 = b << 9;
    int e0 = boff[b], e1 = boff[b + 1];
    int m = e1 - e0;
    for (int i = t; i < 512; i += 256) hist[i] = 0;
    __syncthreads();
    for (int i = t; i < m; i += 256)
        atomicAdd(&hist[(int)ebuf[e0 + i].y - v0], 1);
    __syncthreads();
    if (t < 64) {                                // wave-0 scan of 512 entries
        int run = 0;
        #pragma unroll
        for (int j = 0; j < 8; ++j) { lptr[8 * t + j] = run; run += hist[8 * t + j]; }
        int inc = run;
        #pragma unroll
        for (int o = 1; o < 64; o <<= 1) {
            int u = __shfl_up(inc, o);
            if (t >= o) inc += u;
        }
        int excl = inc - run;
        #pragma unroll
        for (int j = 0; j < 8; ++j) lptr[8 * t + j] += excl;
    }
    __syncthreads();
    for (int i = t; i < 512; i += 256) {
        int v = v0 + i;
        if (v < N_NODES) {
            rowptr[v] = e0 + lptr[i];
            dinv[v] = rsqrtf((float)(hist[i] + 1));   // +1 self-loop
        }
    }
    __syncthreads();
    for (int i = t; i < 512; i += 256) hist[i] = 0;   // reuse as fill cursor
    __syncthreads();
    for (int i = t; i < m; i += 256) {
        uint2 p = ebuf[e0 + i];
        int lr = (int)p.y - v0;
        int lp = atomicAdd(&hist[lr], 1);
        colidx[e0 + lptr[lr] + lp] = (int)p.x;        // block-private 32KB window
    }
}

// ---------------- GEMM1: h1s = dinv*(x @ W1), bf16x2 packed ----------------
// Lane owns a row (x via float4 VGPR loads); wave owns a 32-col tile (W via
// wave-uniform scalar loads -> SMEM pipe). 32 pure v_fmac per x element.
// No LDS, no barriers.
__global__ __launch_bounds__(256) void k_gemm1(const float* __restrict__ x,
                                               const float* __restrict__ W,
                                               const float* __restrict__ dinv,
                                               uint* __restrict__ h1b) {
    int wid = threadIdx.x >> 6, lane = threadIdx.x & 63;
    int n0 = __builtin_amdgcn_readfirstlane(wid * 32);   // wave's col tile
    int row = blockIdx.x * 64 + lane;
    int rc = min(row, N_NODES - 1);
    const float* xr = x + (size_t)rc * 128;
    float acc[32] = {};
    for (int k4 = 0; k4 < 32; ++k4) {
        float4 xv = ((const float4*)xr)[k4];
        const float* Wk = W + k4 * 4 * 128 + n0;
        #pragma unroll
        for (int n = 0; n < 32; ++n) acc[n] = fmaf(xv.x, Wk[n], acc[n]);
        #pragma unroll
        for (int n = 0; n < 32; ++n) acc[n] = fmaf(xv.y, Wk[128 + n], acc[n]);
        #pragma unroll
        for (int n = 0; n < 32; ++n) acc[n] = fmaf(xv.z, Wk[256 + n], acc[n]);
        #pragma unroll
        for (int n = 0; n < 32; ++n) acc[n] = fmaf(xv.w, Wk[384 + n], acc[n]);
    }
    if (row < N_NODES) {
        float dv = dinv[row];
        uint o[16];
        #pragma unroll
        for (int i = 0; i < 16; ++i)
            o[i] = bf16_rne(acc[2 * i] * dv) | (bf16_rne(acc[2 * i + 1] * dv) << 16);
        uint4* dst = (uint4*)(h1b + (size_t)row * 64 + n0 / 2);
        #pragma unroll
        for (int i = 0; i < 4; ++i)
            dst[i] = make_uint4(o[4 * i], o[4 * i + 1], o[4 * i + 2], o[4 * i + 3]);
    }
}

// ---------------- agg1: out1 = dv*(sum_s h1s[s] + h1s[v]) + b1 ----------------
// 4 edges per gather instruction: lane (g,c)=(l>>4,l&15); lane loads uint4
// (8 cols) of edge-group g's row. Group partials combined via shfl_xor.
__global__ __launch_bounds__(256) void k_agg1(const uint* __restrict__ h1b,
                                              const int* __restrict__ rowptr,
                                              const int* __restrict__ colidx,
                                              const float* __restrict__ dinv,
                                              const float* __restrict__ b1,
                                              float* __restrict__ out1) {
    const uint4* h1b4 = (const uint4*)h1b;
    int v = __builtin_amdgcn_readfirstlane(blockIdx.x * 4 + (threadIdx.x >> 6));
    if (v >= N_NODES) return;
    int lane = threadIdx.x & 63;
    int g = lane >> 4, c = lane & 15;
    int beg = rowptr[v], end = rowptr[v + 1];
    float a0 = 0, a1 = 0, a2 = 0, a3 = 0, a4 = 0, a5 = 0, a6 = 0, a7 = 0;
    #define ACC8(u) { a0 += bf_lo(u.x); a1 += bf_hi(u.x); a2 += bf_lo(u.y); a3 += bf_hi(u.y); \
                      a4 += bf_lo(u.z); a5 += bf_hi(u.z); a6 += bf_lo(u.w); a7 += bf_hi(u.w); }
    if (g == 0) {                        // self-loop handled once by group 0
        uint4 us = h1b4[(size_t)v * 16 + c];
        ACC8(us);
    }
    int p = beg + g;
    for (; p + 4 < end; p += 8) {        // edges p and p+4 (stride 4 per group)
        uint4 u0 = h1b4[(size_t)colidx[p] * 16 + c];
        uint4 u1 = h1b4[(size_t)colidx[p + 4] * 16 + c];
        ACC8(u0);
        ACC8(u1);
    }
    if (p < end) {
        uint4 u = h1b4[(size_t)colidx[p] * 16 + c];
        ACC8(u);
    }
    #undef ACC8
    // combine 4 edge-groups (lanes differing in bits 4,5)
    a0 += __shfl_xor(a0, 16); a0 += __shfl_xor(a0, 32);
    a1 += __shfl_xor(a1, 16); a1 += __shfl_xor(a1, 32);
    a2 += __shfl_xor(a2, 16); a2 += __shfl_xor(a2, 32);
    a3 += __shfl_xor(a3, 16); a3 += __shfl_xor(a3, 32);
    a4 += __shfl_xor(a4, 16); a4 += __shfl_xor(a4, 32);
    a5 += __shfl_xor(a5, 16); a5 += __shfl_xor(a5, 32);
    a6 += __shfl_xor(a6, 16); a6 += __shfl_xor(a6, 32);
    a7 += __shfl_xor(a7, 16); a7 += __shfl_xor(a7, 32);
    if (g == 0) {                        // lanes 0-15 write cols [8c, 8c+8)
        float dv = dinv[v];
        const float* bp = b1 + 8 * c;
        float4 o0, o1;
        o0.x = fmaf(dv, a0, bp[0]); o0.y = fmaf(dv, a1, bp[1]);
        o0.z = fmaf(dv, a2, bp[2]); o0.w = fmaf(dv, a3, bp[3]);
        o1.x = fmaf(dv, a4, bp[4]); o1.y = fmaf(dv, a5, bp[5]);
        o1.z = fmaf(dv, a6, bp[6]); o1.w = fmaf(dv, a7, bp[7]);
        float4* dst = (float4*)(out1 + (size_t)v * 128 + 8 * c);
        dst[0] = o0;
        dst[1] = o1;
    }
}

// ---------------- BN stats ----------------
__global__ __launch_bounds__(256) void k_bnstats(const float* __restrict__ out1,
                                                 float* __restrict__ sum,
                                                 float* __restrict__ sumsq) {
    int f = threadIdx.x & 127;
    int n0 = blockIdx.x * 2 + (threadIdx.x >> 7);
    float s = 0.f, ss = 0.f;
    for (int n = n0; n < N_NODES; n += gridDim.x * 2) {
        float v = out1[n * 128 + f];
        s += v;
        ss += v * v;
    }
    __shared__ float ls[256], lss[256];
    ls[threadIdx.x] = s;
    lss[threadIdx.x] = ss;
    __syncthreads();
    if (threadIdx.x < 128) {
        atomicAdd(&sum[f], ls[threadIdx.x] + ls[threadIdx.x + 128]);
        atomicAdd(&sumsq[f], lss[threadIdx.x] + lss[threadIdx.x + 128]);
    }
}

__global__ void k_bnfinal(const float* __restrict__ sum, const float* __restrict__ sumsq,
                          const float* __restrict__ gamma, const float* __restrict__ beta,
                          float* __restrict__ scale, float* __restrict__ shift) {
    int f = threadIdx.x;   // 128 threads
    float mean = sum[f] * (1.f / N_NODES);
    float var = sumsq[f] * (1.f / N_NODES) - mean * mean;
    float rstd = rsqrtf(var + BN_EPS);
    float sc = gamma[f] * rstd;
    scale[f] = sc;
    shift[f] = beta[f] - mean * sc;
}

// ---------------- BN apply + ReLU -> bf16x2 packed out1b ----------------
__global__ __launch_bounds__(256) void k_bnapply2(const float* __restrict__ out1,
                                                  const float* __restrict__ scale,
                                                  const float* __restrict__ shift,
                                                  uint* __restrict__ out1b) {
    int i = blockIdx.x * 256 + threadIdx.x;        // float4 index
    float4 v = ((const float4*)out1)[i];
    float4 sc = ((const float4*)scale)[i & 31];
    float4 sh = ((const float4*)shift)[i & 31];
    v.x = fmaxf(fmaf(v.x, sc.x, sh.x), 0.f);
    v.y = fmaxf(fmaf(v.y, sc.y, sh.y), 0.f);
    v.z = fmaxf(fmaf(v.z, sc.z, sh.z), 0.f);
    v.w = fmaxf(fmaf(v.w, sc.w, sh.w), 0.f);
    uint2 o;
    o.x = bf16_rne(v.x) | (bf16_rne(v.y) << 16);
    o.y = bf16_rne(v.z) | (bf16_rne(v.w) << 16);
    ((uint2*)out1b)[i] = o;
}

// ---------------- GEMM2: h2s = dinv*(out1b @ W2), bf16 in, bf16 out ----------------
__global__ __launch_bounds__(256) void k_gemm2(const uint* __restrict__ out1b,
                                               const float* __restrict__ W2,
                                               const float* __restrict__ dinv,
                                               ushort* __restrict__ h2b) {
    __shared__ float W2s[128 * 40 + 64];
    {
        const float4* Wg = (const float4*)W2;
        float4* Wl = (float4*)W2s;
        #pragma unroll
        for (int i = 0; i < 5; ++i) Wl[threadIdx.x + 256 * i] = Wg[threadIdx.x + 256 * i];
    }
    __syncthreads();
    int wid = threadIdx.x >> 6, lane = threadIdx.x & 63;
    int r0 = __builtin_amdgcn_readfirstlane(blockIdx.x * 32 + wid * 8);
    float acc[8] = {};
    #pragma unroll 8
    for (int k2 = 0; k2 < 64; ++k2) {
        float w0 = W2s[(2 * k2) * 40 + lane];       // lanes 40-63: junk, unused
        float w1 = W2s[(2 * k2 + 1) * 40 + lane];
        #pragma unroll
        for (int j = 0; j < 8; ++j) {
            uint u = out1b[(r0 + j) * 64 + k2];     // uniform -> s_load
            acc[j] = fmaf(bf_lo(u), w0, acc[j]);
            acc[j] = fmaf(bf_hi(u), w1, acc[j]);
        }
    }
    if (lane < F_OUT) {
        #pragma unroll
        for (int j = 0; j < 8; ++j) {
            float dv = dinv[r0 + j];
            h2b[(r0 + j) * F_OUT + lane] = (ushort)bf16_rne(acc[j] * dv);
        }
    }
}

// ---------------- agg2 + b2 + log_softmax ----------------
// 6 edges per gather instruction: 6 groups x 10 lanes, uint2 (4 cols) per
// lane. Per-lane partials -> LDS -> lanes 0-39 sum 6 group slots -> softmax.
__global__ __launch_bounds__(256) void k_agg2(const uint2* __restrict__ h2u2,
                                              const int* __restrict__ rowptr,
                                              const int* __restrict__ colidx,
                                              const float* __restrict__ dinv,
                                              const float* __restrict__ b2,
                                              float* __restrict__ out) {
    __shared__ float sm[4][64][4];
    int wid = threadIdx.x >> 6;
    int v = __builtin_amdgcn_readfirstlane(blockIdx.x * 4 + wid);
    if (v >= N_NODES) return;
    int lane = threadIdx.x & 63;
    int g = lane / 10;
    int c = lane - g * 10;           // chunk: cols [4c, 4c+4)
    bool act = g < 6;
    int beg = rowptr[v], end = rowptr[v + 1];
    float a0 = 0, a1 = 0, a2 = 0, a3 = 0;
    if (act) {
        if (g == 0) {                // self-loop once
            uint2 u = h2u2[(size_t)v * 10 + c];
            a0 += bf_lo(u.x); a1 += bf_hi(u.x); a2 += bf_lo(u.y); a3 += bf_hi(u.y);
        }
        int p = beg + g;
        for (; p + 6 < end; p += 12) {   // edges p and p+6 (stride 6 per group)
            uint2 u0 = h2u2[(size_t)colidx[p] * 10 + c];
            uint2 u1 = h2u2[(size_t)colidx[p + 6] * 10 + c];
            a0 += bf_lo(u0.x) + bf_lo(u1.x);
            a1 += bf_hi(u0.x) + bf_hi(u1.x);
            a2 += bf_lo(u0.y) + bf_lo(u1.y);
            a3 += bf_hi(u0.y) + bf_hi(u1.y);
        }
        if (p < end) {
            uint2 u = h2u2[(size_t)colidx[p] * 10 + c];
            a0 += bf_lo(u.x); a1 += bf_hi(u.x); a2 += bf_lo(u.y); a3 += bf_hi(u.y);
        }
    }
    // deposit partials (all 64 lanes; lanes 60-63 write zeros, never read)
    float4* slot = (float4*)&sm[wid][lane][0];
    *slot = make_float4(a0, a1, a2, a3);
    asm volatile("s_waitcnt lgkmcnt(0)" ::: "memory");
    __builtin_amdgcn_sched_barrier(0);
    float z = -1e30f;
    if (lane < F_OUT) {
        int cc = lane >> 2, jj = lane & 3;
        float s = sm[wid][cc][jj]      + sm[wid][10 + cc][jj] + sm[wid][20 + cc][jj]
                + sm[wid][30 + cc][jj] + sm[wid][40 + cc][jj] + sm[wid][50 + cc][jj];
        z = fmaf(dinv[v], s, b2[lane]);
    }
    float m = z;
    #pragma unroll
    for (int off = 32; off; off >>= 1) m = fmaxf(m, __shfl_xor(m, off));
    float e = (lane < F_OUT) ? __expf(z - m) : 0.f;
    float ssum = e;
    #pragma unroll
    for (int off = 32; off; off >>= 1) ssum += __shfl_xor(ssum, off);
    if (lane < F_OUT) out[(size_t)v * F_OUT + lane] = z - m - __logf(ssum);
}

// ---------------- launch ----------------
extern "C" void kernel_launch(void* const* d_in, const int* in_sizes, int n_in,
                              void* d_out, int out_size, void* d_ws, size_t ws_size,
                              hipStream_t stream) {
    const float* x     = (const float*)d_in[0];
    const float* W1    = (const float*)d_in[1];
    const float* b1    = (const float*)d_in[2];
    const float* gamma = (const float*)d_in[3];
    const float* beta  = (const float*)d_in[4];
    const float* W2    = (const float*)d_in[5];
    const float* b2    = (const float*)d_in[6];
    const int* esrc    = (const int*)d_in[7];
    const int* edst    = (const int*)d_in[8];
    float* out         = (float*)d_out;

    // workspace layout
    char* w = (char*)d_ws;
    size_t off = 0;
    auto alloc = [&](size_t bytes) -> void* {
        void* p = w + off;
        off = (off + bytes + 255) & ~(size_t)255;
        return p;
    };
    int*   gcnt   = (int*)alloc(256 * 4);
    int*   boff   = (int*)alloc((NBUCK + 1) * 4);
    int*   gfill  = (int*)alloc(NBUCK * 4);
    int*   rowptr = (int*)alloc((N_NODES + 1) * 4);
    float* dinv   = (float*)alloc(N_NODES * 4);
    int*   colidx = (int*)alloc((size_t)N_EDGES * 4);
    uint*  h1b    = (uint*)alloc((size_t)N_NODES * 64 * 4);    // bf16x2 [N,128]
    float* out1   = (float*)alloc((size_t)N_NODES * F_HID * 4);
    ushort* h2b   = (ushort*)alloc((size_t)N_NODES * F_OUT * 2); // bf16 [N,40]
    float* bnsum  = (float*)alloc(128 * 4);
    float* bnsq   = (float*)alloc(128 * 4);
    float* scale  = (float*)alloc(128 * 4);
    float* shift  = (float*)alloc(128 * 4);
    uint2* ebuf   = (uint2*)h1b;    // 12.8MB, dead before gemm1 writes h1b
    uint*  out1b  = h1b;            // h1b dead after agg1; reuse: bf16x2 [N,128]

    (void)ws_size; (void)in_sizes; (void)n_in; (void)out_size;

    hipMemsetAsync(gcnt,  0, 256 * 4, stream);
    hipMemsetAsync(bnsum, 0, 128 * 4, stream);
    hipMemsetAsync(bnsq,  0, 128 * 4, stream);

    k_hist <<<NCHUNK, 256, 0, stream>>>(edst, gcnt);
    k_bscan<<<1, 256, 0, stream>>>(gcnt, boff, gfill, rowptr);
    k_part <<<NCHUNK, 256, 0, stream>>>(esrc, edst, gfill, ebuf);
    k_csr  <<<NBUCK, 256, 0, stream>>>(ebuf, boff, rowptr, dinv, colidx);

    k_gemm1<<<(N_NODES + 63) / 64, 256, 0, stream>>>(x, W1, dinv, h1b);
    k_agg1<<<(N_NODES + 3) / 4, 256, 0, stream>>>(h1b, rowptr, colidx, dinv, b1, out1);

    k_bnstats<<<512, 256, 0, stream>>>(out1, bnsum, bnsq);
    k_bnfinal<<<1, 128, 0, stream>>>(bnsum, bnsq, gamma, beta, scale, shift);
    k_bnapply2<<<N_NODES * F_HID / 4 / 256, 256, 0, stream>>>(out1, scale, shift, out1b);

    k_gemm2<<<N_NODES / 32, 256, 0, stream>>>(out1b, W2, dinv, h2b);
    k_agg2<<<(N_NODES + 3) / 4, 256, 0, stream>>>((const uint2*)h2b, rowptr, colidx, dinv, b2, out);
}

// Round 8
// 278.435 us; speedup vs baseline: 2.1129x; 1.2370x over previous
//
#include <hip/hip_runtime.h>
#include <cstdint>
#include <cstddef>

constexpr int N_NODES = 100000;
constexpr int N_EDGES = 1600000;
constexpr int F_IN   = 128;
constexpr int F_HID  = 128;
constexpr int F_OUT  = 40;
constexpr float BN_EPS = 1e-5f;

constexpr int NBUCK  = 196;      // ceil(100000 / 512), bucket = dst >> 9
constexpr int ECHUNK = 4096;     // edges per partition block
constexpr int NCHUNK = (N_EDGES + ECHUNK - 1) / ECHUNK;   // 391

typedef unsigned int uint;
typedef unsigned short ushort;
typedef __attribute__((ext_vector_type(8))) short short8v;   // 8 bf16 (4 VGPRs)
typedef __attribute__((ext_vector_type(4))) float f32x4;     // MFMA acc

// ---------------- helpers ----------------
__device__ inline uint bf16_rne(float f) {
    uint u = __float_as_uint(f);
    return (u + 0x7fffu + ((u >> 16) & 1u)) >> 16;
}
__device__ inline float bf_lo(uint u) { return __uint_as_float(u << 16); }
__device__ inline float bf_hi(uint u) { return __uint_as_float(u & 0xffff0000u); }

// ---------------- CSR build: bucketed two-level ----------------
__global__ __launch_bounds__(256) void k_hist(const int* __restrict__ dst,
                                              int* __restrict__ gcnt) {
    __shared__ int hist[NBUCK];
    for (int i = threadIdx.x; i < NBUCK; i += 256) hist[i] = 0;
    __syncthreads();
    int base = blockIdx.x * ECHUNK;
    int n = min(ECHUNK, N_EDGES - base);
    for (int i = threadIdx.x; i < n; i += 256)
        atomicAdd(&hist[dst[base + i] >> 9], 1);
    __syncthreads();
    for (int i = threadIdx.x; i < NBUCK; i += 256)
        if (hist[i]) atomicAdd(&gcnt[i], hist[i]);
}

__global__ void k_bscan(const int* __restrict__ gcnt, int* __restrict__ boff,
                        int* __restrict__ gfill, int* __restrict__ rowptr) {
    __shared__ int s[256];
    int t = threadIdx.x;
    int c = (t < NBUCK) ? gcnt[t] : 0;
    s[t] = c;
    __syncthreads();
    #pragma unroll
    for (int o = 1; o < 256; o <<= 1) {
        int v = (t >= o) ? s[t - o] : 0;
        __syncthreads();
        s[t] += v;
        __syncthreads();
    }
    if (t < NBUCK) { int e = s[t] - c; boff[t] = e; gfill[t] = e; }
    if (t == 0) { boff[NBUCK] = N_EDGES; rowptr[N_NODES] = N_EDGES; }
}

__global__ __launch_bounds__(256) void k_part(const int* __restrict__ src,
                                              const int* __restrict__ dst,
                                              int* __restrict__ gfill,
                                              uint2* __restrict__ ebuf) {
    __shared__ uint2 pairs[ECHUNK];          // 32 KB
    __shared__ uint  gd[ECHUNK];             // 16 KB
    __shared__ int hist[NBUCK], loff[NBUCK], gpos[NBUCK], lfill[NBUCK];
    __shared__ int sc[256];
    int t = threadIdx.x;
    for (int i = t; i < NBUCK; i += 256) { hist[i] = 0; lfill[i] = 0; }
    __syncthreads();
    int base = blockIdx.x * ECHUNK;
    int n = min(ECHUNK, N_EDGES - base);
    for (int i = t; i < n; i += 256)
        atomicAdd(&hist[dst[base + i] >> 9], 1);
    __syncthreads();
    int c = (t < NBUCK) ? hist[t] : 0;
    sc[t] = c;
    __syncthreads();
    #pragma unroll
    for (int o = 1; o < 256; o <<= 1) {
        int v = (t >= o) ? sc[t - o] : 0;
        __syncthreads();
        sc[t] += v;
        __syncthreads();
    }
    if (t < NBUCK) {
        loff[t] = sc[t] - c;
        gpos[t] = c ? atomicAdd(&gfill[t], c) : 0;
    }
    __syncthreads();
    for (int i = t; i < n; i += 256) {
        int d = dst[base + i];
        int s2 = src[base + i];
        int b = d >> 9;
        int lp = atomicAdd(&lfill[b], 1);
        int idx = loff[b] + lp;
        pairs[idx] = make_uint2((uint)s2, (uint)d);
        gd[idx] = (uint)(gpos[b] + lp);
    }
    __syncthreads();
    for (int i = t; i < n; i += 256)
        ebuf[gd[i]] = pairs[i];                 // coalesced runs (~21 edges)
}

__global__ __launch_bounds__(256) void k_csr(const uint2* __restrict__ ebuf,
                                             const int* __restrict__ boff,
                                             int* __restrict__ rowptr,
                                             float* __restrict__ dinv,
                                             int* __restrict__ colidx) {
    __shared__ int hist[512];
    __shared__ int lptr[512];
    int t = threadIdx.x;
    int b = blockIdx.x;
    int v0 = b << 9;
    int e0 = boff[b], e1 = boff[b + 1];
    int m = e1 - e0;
    for (int i = t; i < 512; i += 256) hist[i] = 0;
    __syncthreads();
    for (int i = t; i < m; i += 256)
        atomicAdd(&hist[(int)ebuf[e0 + i].y - v0], 1);
    __syncthreads();
    if (t < 64) {                                // wave-0 scan of 512 entries
        int run = 0;
        #pragma unroll
        for (int j = 0; j < 8; ++j) { lptr[8 * t + j] = run; run += hist[8 * t + j]; }
        int inc = run;
        #pragma unroll
        for (int o = 1; o < 64; o <<= 1) {
            int u = __shfl_up(inc, o);
            if (t >= o) inc += u;
        }
        int excl = inc - run;
        #pragma unroll
        for (int j = 0; j < 8; ++j) lptr[8 * t + j] += excl;
    }
    __syncthreads();
    for (int i = t; i < 512; i += 256) {
        int v = v0 + i;
        if (v < N_NODES) {
            rowptr[v] = e0 + lptr[i];
            dinv[v] = rsqrtf((float)(hist[i] + 1));   // +1 self-loop
        }
    }
    __syncthreads();
    for (int i = t; i < 512; i += 256) hist[i] = 0;   // reuse as fill cursor
    __syncthreads();
    for (int i = t; i < m; i += 256) {
        uint2 p = ebuf[e0 + i];
        int lr = (int)p.y - v0;
        int lp = atomicAdd(&hist[lr], 1);
        colidx[e0 + lptr[lr] + lp] = (int)p.x;        // block-private 32KB window
    }
}

// ---------------- weight cast: W1 -> bf16 [n][k]; W2 -> bf16 [48][128] ----------------
__global__ __launch_bounds__(256) void k_wcast(const float* __restrict__ W1,
                                               const float* __restrict__ W2,
                                               ushort* __restrict__ w1b,
                                               ushort* __restrict__ w2b) {
    int i = blockIdx.x * 256 + threadIdx.x;
    if (i < 128 * 128) {
        int n = i >> 7, k = i & 127;
        w1b[i] = (ushort)bf16_rne(W1[k * 128 + n]);
    }
    if (i < 48 * 128) {
        int c = i >> 7, k = i & 127;
        w2b[i] = (c < F_OUT) ? (ushort)bf16_rne(W2[k * F_OUT + c]) : (ushort)0;
    }
}

// ---------------- GEMM1 (MFMA): h1s = dinv*(x @ W1), bf16x2 packed ----------------
// Block = 64 rows, wave = 16 rows. A-frag: row=lane&15, k=8*(lane>>4)+e from x
// (fp32 -> bf16). B-frag: col=lane&15 of w1b [n][k]. Epilogue via LDS.
__global__ __launch_bounds__(256) void k_gemm1(const float* __restrict__ x,
                                               const ushort* __restrict__ w1b,
                                               const float* __restrict__ dinv,
                                               uint* __restrict__ h1b) {
    __shared__ float sm[64 * 132];
    int wid = threadIdx.x >> 6, lane = threadIdx.x & 63;
    int li = lane & 15, kg = lane >> 4;
    int row = blockIdx.x * 64 + wid * 16 + li;
    int rc = min(row, N_NODES - 1);
    const float* xr = x + (size_t)rc * 128;
    f32x4 acc[8] = {};
    #pragma unroll
    for (int kk = 0; kk < 4; ++kk) {
        int k0 = kk * 32 + kg * 8;
        float4 xv0 = *(const float4*)(xr + k0);
        float4 xv1 = *(const float4*)(xr + k0 + 4);
        short8v a;
        a[0] = (short)bf16_rne(xv0.x); a[1] = (short)bf16_rne(xv0.y);
        a[2] = (short)bf16_rne(xv0.z); a[3] = (short)bf16_rne(xv0.w);
        a[4] = (short)bf16_rne(xv1.x); a[5] = (short)bf16_rne(xv1.y);
        a[6] = (short)bf16_rne(xv1.z); a[7] = (short)bf16_rne(xv1.w);
        #pragma unroll
        for (int n = 0; n < 8; ++n) {
            short8v b = *(const short8v*)(w1b + (n * 16 + li) * 128 + k0);
            acc[n] = __builtin_amdgcn_mfma_f32_16x16x32_bf16(a, b, acc[n], 0, 0, 0);
        }
    }
    // stage: C/D layout col=lane&15, row=4*(lane>>4)+j
    #pragma unroll
    for (int n = 0; n < 8; ++n)
        #pragma unroll
        for (int j = 0; j < 4; ++j)
            sm[(wid * 16 + kg * 4 + j) * 132 + n * 16 + li] = acc[n][j];
    __syncthreads();
    // pack: thread t -> row t>>2, col block (t&3)*32
    int rr = threadIdx.x >> 2, cb = (threadIdx.x & 3) * 32;
    int grow = blockIdx.x * 64 + rr;
    if (grow < N_NODES) {
        float dv = dinv[grow];
        const float4* sp4 = (const float4*)(sm + rr * 132 + cb);
        uint4 ov[4];
        #pragma unroll
        for (int q = 0; q < 4; ++q) {
            float4 e0 = sp4[2 * q], e1 = sp4[2 * q + 1];
            ov[q].x = bf16_rne(e0.x * dv) | (bf16_rne(e0.y * dv) << 16);
            ov[q].y = bf16_rne(e0.z * dv) | (bf16_rne(e0.w * dv) << 16);
            ov[q].z = bf16_rne(e1.x * dv) | (bf16_rne(e1.y * dv) << 16);
            ov[q].w = bf16_rne(e1.z * dv) | (bf16_rne(e1.w * dv) << 16);
        }
        uint4* dst = (uint4*)(h1b + (size_t)grow * 64 + cb / 2);
        #pragma unroll
        for (int q = 0; q < 4; ++q) dst[q] = ov[q];
    }
}

// ---------------- agg1: out1 = dv*(sum_s h1s[s] + h1s[v]) + b1 ----------------
__global__ __launch_bounds__(256) void k_agg1(const uint* __restrict__ h1b,
                                              const int* __restrict__ rowptr,
                                              const int* __restrict__ colidx,
                                              const float* __restrict__ dinv,
                                              const float* __restrict__ b1,
                                              float* __restrict__ out1) {
    const uint4* h1b4 = (const uint4*)h1b;
    int v = __builtin_amdgcn_readfirstlane(blockIdx.x * 4 + (threadIdx.x >> 6));
    if (v >= N_NODES) return;
    int lane = threadIdx.x & 63;
    int g = lane >> 4, c = lane & 15;
    int beg = rowptr[v], end = rowptr[v + 1];
    float a0 = 0, a1 = 0, a2 = 0, a3 = 0, a4 = 0, a5 = 0, a6 = 0, a7 = 0;
    #define ACC8(u) { a0 += bf_lo(u.x); a1 += bf_hi(u.x); a2 += bf_lo(u.y); a3 += bf_hi(u.y); \
                      a4 += bf_lo(u.z); a5 += bf_hi(u.z); a6 += bf_lo(u.w); a7 += bf_hi(u.w); }
    if (g == 0) {                        // self-loop handled once by group 0
        uint4 us = h1b4[(size_t)v * 16 + c];
        ACC8(us);
    }
    int p = beg + g;
    for (; p + 4 < end; p += 8) {        // edges p and p+4 (stride 4 per group)
        uint4 u0 = h1b4[(size_t)colidx[p] * 16 + c];
        uint4 u1 = h1b4[(size_t)colidx[p + 4] * 16 + c];
        ACC8(u0);
        ACC8(u1);
    }
    if (p < end) {
        uint4 u = h1b4[(size_t)colidx[p] * 16 + c];
        ACC8(u);
    }
    #undef ACC8
    a0 += __shfl_xor(a0, 16); a0 += __shfl_xor(a0, 32);
    a1 += __shfl_xor(a1, 16); a1 += __shfl_xor(a1, 32);
    a2 += __shfl_xor(a2, 16); a2 += __shfl_xor(a2, 32);
    a3 += __shfl_xor(a3, 16); a3 += __shfl_xor(a3, 32);
    a4 += __shfl_xor(a4, 16); a4 += __shfl_xor(a4, 32);
    a5 += __shfl_xor(a5, 16); a5 += __shfl_xor(a5, 32);
    a6 += __shfl_xor(a6, 16); a6 += __shfl_xor(a6, 32);
    a7 += __shfl_xor(a7, 16); a7 += __shfl_xor(a7, 32);
    if (g == 0) {                        // lanes 0-15 write cols [8c, 8c+8)
        float dv = dinv[v];
        const float* bp = b1 + 8 * c;
        float4 o0, o1;
        o0.x = fmaf(dv, a0, bp[0]); o0.y = fmaf(dv, a1, bp[1]);
        o0.z = fmaf(dv, a2, bp[2]); o0.w = fmaf(dv, a3, bp[3]);
        o1.x = fmaf(dv, a4, bp[4]); o1.y = fmaf(dv, a5, bp[5]);
        o1.z = fmaf(dv, a6, bp[6]); o1.w = fmaf(dv, a7, bp[7]);
        float4* dst = (float4*)(out1 + (size_t)v * 128 + 8 * c);
        dst[0] = o0;
        dst[1] = o1;
    }
}

// ---------------- BN stats ----------------
__global__ __launch_bounds__(256) void k_bnstats(const float* __restrict__ out1,
                                                 float* __restrict__ sum,
                                                 float* __restrict__ sumsq) {
    int f = threadIdx.x & 127;
    int n0 = blockIdx.x * 2 + (threadIdx.x >> 7);
    float s = 0.f, ss = 0.f;
    for (int n = n0; n < N_NODES; n += gridDim.x * 2) {
        float v = out1[n * 128 + f];
        s += v;
        ss += v * v;
    }
    __shared__ float ls[256], lss[256];
    ls[threadIdx.x] = s;
    lss[threadIdx.x] = ss;
    __syncthreads();
    if (threadIdx.x < 128) {
        atomicAdd(&sum[f], ls[threadIdx.x] + ls[threadIdx.x + 128]);
        atomicAdd(&sumsq[f], lss[threadIdx.x] + lss[threadIdx.x + 128]);
    }
}

__global__ void k_bnfinal(const float* __restrict__ sum, const float* __restrict__ sumsq,
                          const float* __restrict__ gamma, const float* __restrict__ beta,
                          float* __restrict__ scale, float* __restrict__ shift) {
    int f = threadIdx.x;   // 128 threads
    float mean = sum[f] * (1.f / N_NODES);
    float var = sumsq[f] * (1.f / N_NODES) - mean * mean;
    float rstd = rsqrtf(var + BN_EPS);
    float sc = gamma[f] * rstd;
    scale[f] = sc;
    shift[f] = beta[f] - mean * sc;
}

// ---------------- GEMM2 (MFMA, BN+ReLU fused per-element in A-frag load) ----------------
// h2s = dinv * (relu(bn(out1)) @ W2), bf16 out. 3 n-tiles (48 cols, 40 used).
__global__ __launch_bounds__(256) void k_gemm2(const float* __restrict__ out1,
                                               const ushort* __restrict__ w2b,
                                               const float* __restrict__ scale,
                                               const float* __restrict__ shift,
                                               const float* __restrict__ dinv,
                                               ushort* __restrict__ h2b) {
    __shared__ float sm[64 * 52];
    int wid = threadIdx.x >> 6, lane = threadIdx.x & 63;
    int li = lane & 15, kg = lane >> 4;
    int row = blockIdx.x * 64 + wid * 16 + li;
    int rc = min(row, N_NODES - 1);
    const float* xr = out1 + (size_t)rc * 128;
    f32x4 acc[3] = {};
    #pragma unroll
    for (int kk = 0; kk < 4; ++kk) {
        int k0 = kk * 32 + kg * 8;
        float4 xv0 = *(const float4*)(xr + k0);
        float4 xv1 = *(const float4*)(xr + k0 + 4);
        float4 sc0 = *(const float4*)(scale + k0);
        float4 sc1 = *(const float4*)(scale + k0 + 4);
        float4 sh0 = *(const float4*)(shift + k0);
        float4 sh1 = *(const float4*)(shift + k0 + 4);
        float e0 = fmaxf(fmaf(xv0.x, sc0.x, sh0.x), 0.f);
        float e1 = fmaxf(fmaf(xv0.y, sc0.y, sh0.y), 0.f);
        float e2 = fmaxf(fmaf(xv0.z, sc0.z, sh0.z), 0.f);
        float e3 = fmaxf(fmaf(xv0.w, sc0.w, sh0.w), 0.f);
        float e4 = fmaxf(fmaf(xv1.x, sc1.x, sh1.x), 0.f);
        float e5 = fmaxf(fmaf(xv1.y, sc1.y, sh1.y), 0.f);
        float e6 = fmaxf(fmaf(xv1.z, sc1.z, sh1.z), 0.f);
        float e7 = fmaxf(fmaf(xv1.w, sc1.w, sh1.w), 0.f);
        short8v a;
        a[0] = (short)bf16_rne(e0); a[1] = (short)bf16_rne(e1);
        a[2] = (short)bf16_rne(e2); a[3] = (short)bf16_rne(e3);
        a[4] = (short)bf16_rne(e4); a[5] = (short)bf16_rne(e5);
        a[6] = (short)bf16_rne(e6); a[7] = (short)bf16_rne(e7);
        #pragma unroll
        for (int n = 0; n < 3; ++n) {
            short8v b = *(const short8v*)(w2b + (n * 16 + li) * 128 + k0);
            acc[n] = __builtin_amdgcn_mfma_f32_16x16x32_bf16(a, b, acc[n], 0, 0, 0);
        }
    }
    #pragma unroll
    for (int n = 0; n < 3; ++n)
        #pragma unroll
        for (int j = 0; j < 4; ++j)
            sm[(wid * 16 + kg * 4 + j) * 52 + n * 16 + li] = acc[n][j];
    __syncthreads();
    // pack: one thread per row (threads 0-63), 40 ushorts = 5 uint4
    int rr = threadIdx.x;
    int grow = blockIdx.x * 64 + rr;
    if (rr < 64 && grow < N_NODES) {
        float dv = dinv[grow];
        const float* sp = sm + rr * 52;
        uint o[20];
        #pragma unroll
        for (int i = 0; i < 20; ++i)
            o[i] = bf16_rne(sp[2 * i] * dv) | (bf16_rne(sp[2 * i + 1] * dv) << 16);
        uint4* dst = (uint4*)(h2b + (size_t)grow * F_OUT);
        #pragma unroll
        for (int q = 0; q < 5; ++q)
            dst[q] = make_uint4(o[4 * q], o[4 * q + 1], o[4 * q + 2], o[4 * q + 3]);
    }
}

// ---------------- agg2 + b2 + log_softmax ----------------
__global__ __launch_bounds__(256) void k_agg2(const uint2* __restrict__ h2u2,
                                              const int* __restrict__ rowptr,
                                              const int* __restrict__ colidx,
                                              const float* __restrict__ dinv,
                                              const float* __restrict__ b2,
                                              float* __restrict__ out) {
    __shared__ float sm[4][64][4];
    int wid = threadIdx.x >> 6;
    int v = __builtin_amdgcn_readfirstlane(blockIdx.x * 4 + wid);
    if (v >= N_NODES) return;
    int lane = threadIdx.x & 63;
    int g = lane / 10;
    int c = lane - g * 10;           // chunk: cols [4c, 4c+4)
    bool act = g < 6;
    int beg = rowptr[v], end = rowptr[v + 1];
    float a0 = 0, a1 = 0, a2 = 0, a3 = 0;
    if (act) {
        if (g == 0) {                // self-loop once
            uint2 u = h2u2[(size_t)v * 10 + c];
            a0 += bf_lo(u.x); a1 += bf_hi(u.x); a2 += bf_lo(u.y); a3 += bf_hi(u.y);
        }
        int p = beg + g;
        for (; p + 6 < end; p += 12) {   // edges p and p+6 (stride 6 per group)
            uint2 u0 = h2u2[(size_t)colidx[p] * 10 + c];
            uint2 u1 = h2u2[(size_t)colidx[p + 6] * 10 + c];
            a0 += bf_lo(u0.x) + bf_lo(u1.x);
            a1 += bf_hi(u0.x) + bf_hi(u1.x);
            a2 += bf_lo(u0.y) + bf_lo(u1.y);
            a3 += bf_hi(u0.y) + bf_hi(u1.y);
        }
        if (p < end) {
            uint2 u = h2u2[(size_t)colidx[p] * 10 + c];
            a0 += bf_lo(u.x); a1 += bf_hi(u.x); a2 += bf_lo(u.y); a3 += bf_hi(u.y);
        }
    }
    float4* slot = (float4*)&sm[wid][lane][0];
    *slot = make_float4(a0, a1, a2, a3);
    asm volatile("s_waitcnt lgkmcnt(0)" ::: "memory");
    __builtin_amdgcn_sched_barrier(0);
    float z = -1e30f;
    if (lane < F_OUT) {
        int cc = lane >> 2, jj = lane & 3;
        float s = sm[wid][cc][jj]      + sm[wid][10 + cc][jj] + sm[wid][20 + cc][jj]
                + sm[wid][30 + cc][jj] + sm[wid][40 + cc][jj] + sm[wid][50 + cc][jj];
        z = fmaf(dinv[v], s, b2[lane]);
    }
    float m = z;
    #pragma unroll
    for (int off = 32; off; off >>= 1) m = fmaxf(m, __shfl_xor(m, off));
    float e = (lane < F_OUT) ? __expf(z - m) : 0.f;
    float ssum = e;
    #pragma unroll
    for (int off = 32; off; off >>= 1) ssum += __shfl_xor(ssum, off);
    if (lane < F_OUT) out[(size_t)v * F_OUT + lane] = z - m - __logf(ssum);
}

// ---------------- launch ----------------
extern "C" void kernel_launch(void* const* d_in, const int* in_sizes, int n_in,
                              void* d_out, int out_size, void* d_ws, size_t ws_size,
                              hipStream_t stream) {
    const float* x     = (const float*)d_in[0];
    const float* W1    = (const float*)d_in[1];
    const float* b1    = (const float*)d_in[2];
    const float* gamma = (const float*)d_in[3];
    const float* beta  = (const float*)d_in[4];
    const float* W2    = (const float*)d_in[5];
    const float* b2    = (const float*)d_in[6];
    const int* esrc    = (const int*)d_in[7];
    const int* edst    = (const int*)d_in[8];
    float* out         = (float*)d_out;

    // workspace layout
    char* w = (char*)d_ws;
    size_t off = 0;
    auto alloc = [&](size_t bytes) -> void* {
        void* p = w + off;
        off = (off + bytes + 255) & ~(size_t)255;
        return p;
    };
    int*   gcnt   = (int*)alloc(256 * 4);
    int*   boff   = (int*)alloc((NBUCK + 1) * 4);
    int*   gfill  = (int*)alloc(NBUCK * 4);
    int*   rowptr = (int*)alloc((N_NODES + 1) * 4);
    float* dinv   = (float*)alloc(N_NODES * 4);
    int*   colidx = (int*)alloc((size_t)N_EDGES * 4);
    uint*  h1b    = (uint*)alloc((size_t)N_NODES * 64 * 4);    // bf16x2 [N,128]
    float* out1   = (float*)alloc((size_t)N_NODES * F_HID * 4);
    ushort* h2b   = (ushort*)alloc((size_t)N_NODES * F_OUT * 2); // bf16 [N,40]
    ushort* w1b   = (ushort*)alloc(128 * 128 * 2);             // bf16 [n][k]
    ushort* w2b   = (ushort*)alloc(48 * 128 * 2);              // bf16 [col][k]
    float* bnsum  = (float*)alloc(128 * 4);
    float* bnsq   = (float*)alloc(128 * 4);
    float* scale  = (float*)alloc(128 * 4);
    float* shift  = (float*)alloc(128 * 4);
    uint2* ebuf   = (uint2*)h1b;    // 12.8MB, dead before gemm1 writes h1b

    (void)ws_size; (void)in_sizes; (void)n_in; (void)out_size;

    hipMemsetAsync(gcnt,  0, 256 * 4, stream);
    hipMemsetAsync(bnsum, 0, 128 * 4, stream);
    hipMemsetAsync(bnsq,  0, 128 * 4, stream);

    k_wcast<<<64, 256, 0, stream>>>(W1, W2, w1b, w2b);

    k_hist <<<NCHUNK, 256, 0, stream>>>(edst, gcnt);
    k_bscan<<<1, 256, 0, stream>>>(gcnt, boff, gfill, rowptr);
    k_part <<<NCHUNK, 256, 0, stream>>>(esrc, edst, gfill, ebuf);
    k_csr  <<<NBUCK, 256, 0, stream>>>(ebuf, boff, rowptr, dinv, colidx);

    k_gemm1<<<(N_NODES + 63) / 64, 256, 0, stream>>>(x, w1b, dinv, h1b);
    k_agg1<<<(N_NODES + 3) / 4, 256, 0, stream>>>(h1b, rowptr, colidx, dinv, b1, out1);

    k_bnstats<<<512, 256, 0, stream>>>(out1, bnsum, bnsq);
    k_bnfinal<<<1, 128, 0, stream>>>(bnsum, bnsq, gamma, beta, scale, shift);

    k_gemm2<<<(N_NODES + 63) / 64, 256, 0, stream>>>(out1, w2b, scale, shift, dinv, h2b);
    k_agg2<<<(N_NODES + 3) / 4, 256, 0, stream>>>((const uint2*)h2b, rowptr, colidx, dinv, b2, out);
}